// Round 2
// baseline (55164.905 us; speedup 1.0000x reference)
//
#include <hip/hip_runtime.h>
#include <hip/hip_bf16.h>

// BaseRNN: B=64,S=512,V=32000,E=512,H=512,L=2
// R2: same persistent-kernel design as R1 (which ran to completion — barrier
// scheme works) but with float tensors read/written as FP32. R1's NaN is only
// constructible by misreading fp32 buffers as bf16 (random mantissa halves
// decode as bf16 NaN ~0.4% of the time -> NaN weights -> NaN h). Reference
// uses fp32 throughout; harness maps float32 -> const float*.
//
// Design: 256 WGs x 256 thr, all resident (49KB LDS, 4 waves). WGs 0..127:
// layer0, 128..255: layer1; 4 output rows each, weights LDS-resident fp32.
// Skewed pipeline: phase p computes h0(t=p) [p<512] and h1(t=p-1) [p>=1];
// one device-wide barrier per phase (monotone counter, agent-scope atomics,
// __threadfence for cross-XCD visibility). h double-buffered fp32 in d_ws.

#define BATCH 64
#define SEQ   512
#define HID   512
#define NWG   256
#define NTHR  256
#define ROWS  4
#define CB    8
#define NCHUNK (BATCH / CB)
#define INPAD 516   // 512 + 4 pad; 516*4B rows stay 16B-aligned

typedef unsigned int u32;

__global__ __launch_bounds__(NTHR, 1) void rnn_persistent(
    const int* __restrict__ x, const int* __restrict__ lengths,
    const float* __restrict__ emb,
    const float* __restrict__ W_ih,
    const float* __restrict__ W_hh,
    const float* __restrict__ b_ih,
    const float* __restrict__ b_hh,
    float* __restrict__ out,
    float* h0buf, float* h1buf, u32* cnt)
{
  __shared__ float Wa[ROWS][HID];    // W_ih[l] rows
  __shared__ float Wb[ROWS][HID];    // W_hh[l] rows
  __shared__ float bias[ROWS];
  __shared__ float in_a[CB][INPAD];  // xe (l0) or h0_new (l1)
  __shared__ float in_b[CB][INPAD];  // own previous h

  const int wg    = blockIdx.x;
  const int tid   = threadIdx.x;
  const int layer = (wg >= 128) ? 1 : 0;
  const int jbase = (layer ? (wg - 128) : wg) * ROWS;

  // ---- stage weights once (fp32, vectorized) ----
  {
    const float* wa_src = W_ih + layer * (HID * HID) + jbase * HID;
    const float* wb_src = W_hh + layer * (HID * HID) + jbase * HID;
    for (int u = tid; u < (ROWS * HID) / 4; u += NTHR) {
      const int r = (4 * u) >> 9, k = (4 * u) & 511;
      *(float4*)&Wa[r][k] = *(const float4*)&wa_src[4 * u];
      *(float4*)&Wb[r][k] = *(const float4*)&wb_src[4 * u];
    }
  }
  if (tid < ROWS) {
    bias[tid] = b_ih[layer * HID + jbase + tid] + b_hh[layer * HID + jbase + tid];
  }
  __syncthreads();

  const int b = tid >> 5;   // batch-in-chunk 0..7
  const int s = tid & 31;   // k-slice lane 0..31

  for (int p = 0; p <= SEQ; ++p) {
    const int rd = (p - 1) & 1;   // p=0 -> buffer 1 (zeroed by memset)
    const int wr = p & 1;
    const bool active = (layer == 0) ? (p < SEQ) : (p >= 1);

    if (active) {
      const int t = (layer == 0) ? p : (p - 1);
      const float* hrd = (layer == 0 ? h0buf : h1buf) + rd * (BATCH * HID);
      float*       hwr = (layer == 0 ? h0buf : h1buf) + wr * (BATCH * HID);
      const float* ard = h0buf + rd * (BATCH * HID);  // layer1 input = h0(t)

      for (int c = 0; c < NCHUNK; ++c) {
        const int gb0 = c * CB;
        for (int u = tid; u < CB * HID; u += NTHR) {
          const int r = u >> 9, k = u & 511;
          in_b[r][k] = hrd[(gb0 + r) * HID + k];
          if (layer == 0) {
            const int tok = x[(gb0 + r) * SEQ + t];
            in_a[r][k] = emb[tok * HID + k];
          } else {
            in_a[r][k] = ard[(gb0 + r) * HID + k];
          }
        }
        __syncthreads();

        float acc[ROWS] = {0.f, 0.f, 0.f, 0.f};
        #pragma unroll
        for (int i = 0; i < 4; ++i) {
          const int kq = 4 * s + 128 * i;
          const float4 a  = *(const float4*)&in_a[b][kq];
          const float4 h4 = *(const float4*)&in_b[b][kq];
          #pragma unroll
          for (int j = 0; j < ROWS; ++j) {
            const float4 wa = *(const float4*)&Wa[j][kq];
            const float4 wb = *(const float4*)&Wb[j][kq];
            acc[j] += a.x * wa.x + a.y * wa.y + a.z * wa.z + a.w * wa.w
                    + h4.x * wb.x + h4.y * wb.y + h4.z * wb.z + h4.w * wb.w;
          }
        }
        #pragma unroll
        for (int d = 16; d >= 1; d >>= 1) {
          acc[0] += __shfl_down(acc[0], d);
          acc[1] += __shfl_down(acc[1], d);
          acc[2] += __shfl_down(acc[2], d);
          acc[3] += __shfl_down(acc[3], d);
        }
        if (s == 0) {
          const int gb = gb0 + b;
          const int len = lengths[gb];
          #pragma unroll
          for (int j = 0; j < ROWS; ++j) {
            const float hn = tanhf(acc[j] + bias[j]);
            const float hv = (t < len) ? hn : in_b[b][jbase + j];  // copy-forward
            __hip_atomic_store(&hwr[gb * HID + jbase + j], hv,
                               __ATOMIC_RELAXED, __HIP_MEMORY_SCOPE_AGENT);
          }
        }
        __syncthreads();  // protect LDS before next chunk restage
      }
    }

    // ---- device-wide barrier (monotone counter) ----
    __threadfence();      // release: drain h stores for cross-XCD visibility
    __syncthreads();
    if (tid == 0) {
      __hip_atomic_fetch_add(cnt, 1u, __ATOMIC_RELAXED, __HIP_MEMORY_SCOPE_AGENT);
      const u32 target = (u32)(p + 1) * NWG;
      while (__hip_atomic_load(cnt, __ATOMIC_RELAXED, __HIP_MEMORY_SCOPE_AGENT) < target)
        __builtin_amdgcn_s_sleep(2);
    }
    __syncthreads();
    __threadfence();      // acquire: invalidate caches before reading fresh h
  }

  // ---- epilogue: h0 final in buffer (S-1)&1 = 1, h1 final in buffer S&1 = 0
  const float* h0f = h0buf + 1 * (BATCH * HID);
  const float* h1f = h1buf + 0 * (BATCH * HID);
  if (tid < 128) {
    const int idx = wg * 128 + tid;        // 256*128 = 32768 = B*H
    const int bb = idx >> 9, j = idx & 511;
    const float v0 = h0f[idx];
    const float v1 = h1f[idx];
    out[idx] = v1;                          // out = hidden[:, -1]
    out[32768 + bb * 1024 + j]       = v0;  // hidden[b][0][j]
    out[32768 + bb * 1024 + 512 + j] = v1;  // hidden[b][1][j]
  }
}

extern "C" void kernel_launch(void* const* d_in, const int* in_sizes, int n_in,
                              void* d_out, int out_size, void* d_ws, size_t ws_size,
                              hipStream_t stream) {
  (void)in_sizes; (void)n_in; (void)out_size; (void)ws_size;
  const int*   x       = (const int*)d_in[0];
  const int*   lengths = (const int*)d_in[1];
  const float* emb     = (const float*)d_in[2];
  const float* W_ih    = (const float*)d_in[3];
  const float* W_hh    = (const float*)d_in[4];
  const float* b_ih    = (const float*)d_in[5];
  const float* b_hh    = (const float*)d_in[6];
  float* out = (float*)d_out;

  float* h0buf = (float*)d_ws;                    // [2][64][512] fp32
  float* h1buf = h0buf + 2 * BATCH * HID;         // [2][64][512] fp32
  u32*   cnt   = (u32*)(h1buf + 2 * BATCH * HID); // barrier counter

  // zero h state (h(-1)=0) + barrier counter; d_ws is re-poisoned each call
  const size_t zero_bytes = (size_t)(4 * BATCH * HID) * sizeof(float) + 256;
  hipMemsetAsync(d_ws, 0, zero_bytes, stream);

  hipLaunchKernelGGL(rnn_persistent, dim3(NWG), dim3(NTHR), 0, stream,
                     x, lengths, emb, W_ih, W_hh, b_ih, b_hh, out,
                     h0buf, h1buf, cnt);
}

// Round 3
// 38261.133 us; speedup vs baseline: 1.4418x; 1.4418x over previous
//
#include <hip/hip_runtime.h>

// BaseRNN B=64,S=512,H=E=512,L=2 — persistent kernel, R3.
// R2 post-mortem: 107us/phase, all latency stall (VALUBusy 5.4%). Cause:
// j-only partitioning forced every WG to re-stage the FULL h/emb set each
// phase (256KB, scalar loads, 16 syncthreads). R3: 2D partition (4 batch-
// groups x 32 row-groups per layer), weights in REGISTERS (64 VGPR/thread,
// no duplication), LDS = inputs only (exactly 64KB), float4 everywhere,
// one stage + one syncthreads per phase, plain stores + release fence.
// Wave tj owns j-quad; lane ks owns k-slice {4ks..4ks+3, 256+4ks..+3};
// binary-exchange wave reduction leaves output o on lane o.

#define BATCH 64
#define SEQ   512
#define HID   512
#define NWG   256
#define NTHR  256
#define CB    16   // batches per WG
#define ROWS  16   // output rows per WG

typedef unsigned int u32;

__device__ __forceinline__ float dot4(const float4 a, const float4 b) {
  return a.x * b.x + a.y * b.y + a.z * b.z + a.w * b.w;
}

__global__ __launch_bounds__(NTHR, 1) void rnn_persistent(
    const int* __restrict__ x, const int* __restrict__ lengths,
    const float* __restrict__ emb,
    const float* __restrict__ W_ih, const float* __restrict__ W_hh,
    const float* __restrict__ b_ih, const float* __restrict__ b_hh,
    float* __restrict__ out,
    float* h0buf, float* h1buf, u32* cnt)
{
  __shared__ __align__(16) float Xa[CB][HID];  // 32KB: emb row (l0) or h0_new (l1)
  __shared__ __align__(16) float Xb[CB][HID];  // 32KB: own previous h

  const int wg    = blockIdx.x;
  const int tid   = threadIdx.x;
  const int layer = wg >> 7;
  const int wl    = wg & 127;
  const int bg    = wl >> 5;         // 0..3  batch-group
  const int rg    = wl & 31;         // 0..31 row-group
  const int bbase = bg * CB;
  const int jbase = rg * ROWS;
  const int tj    = tid >> 6;        // wave id = j-quad 0..3
  const int lane  = tid & 63;        // k-slice

  // ---- weights in registers: thread owns 4 j x 8 k x 2 arrays = 64 VGPRs ----
  float4 wa[2][4], wb[2][4];
  {
    const float* WA = W_ih + layer * (HID * HID);
    const float* WB = W_hh + layer * (HID * HID);
    #pragma unroll
    for (int ji = 0; ji < 4; ++ji) {
      const int j = jbase + tj * 4 + ji;
      #pragma unroll
      for (int i = 0; i < 2; ++i) {
        const int k = i * 256 + 4 * lane;
        wa[i][ji] = *(const float4*)&WA[j * HID + k];
        wb[i][ji] = *(const float4*)&WB[j * HID + k];
      }
    }
  }
  // lane ends the reduction owning output o = lane: b = o>>2, ji = o&3
  const int   b_out  = lane >> 2;
  const int   j_out  = jbase + tj * 4 + (lane & 3);
  const float bias   = b_ih[layer * HID + j_out] + b_hh[layer * HID + j_out];
  const int   len_o  = lengths[bbase + b_out];

  for (int p = 0; p <= SEQ; ++p) {
    const int rd = (p - 1) & 1;      // p=0 reads parity-1 (zeroed by memset)
    const int wr = p & 1;
    const bool active = (layer == 0) ? (p < SEQ) : (p >= 1);

    if (active) {
      const int t = (layer == 0) ? p : (p - 1);
      const float* hrd = (layer ? h1buf : h0buf) + rd * (BATCH * HID);
      float*       hwr = (layer ? h1buf : h0buf) + wr * (BATCH * HID);
      const float* ard = h0buf + rd * (BATCH * HID);  // layer1 input = h0(t)

      // ---- stage inputs: CB x 512 floats per array, float4, coalesced ----
      #pragma unroll
      for (int i = 0; i < 8; ++i) {
        const int u = tid + NTHR * i;        // 0..2047
        const int r = u >> 7;                // row 0..15
        const int c = (u & 127) * 4;         // float4 column
        *(float4*)&Xb[r][c] = *(const float4*)&hrd[(bbase + r) * HID + c];
        if (layer == 0) {
          const int tok = x[(bbase + r) * SEQ + t];
          *(float4*)&Xa[r][c] = *(const float4*)&emb[tok * HID + c];
        } else {
          *(float4*)&Xa[r][c] = *(const float4*)&ard[(bbase + r) * HID + c];
        }
      }
      __syncthreads();

      // ---- compute: 1024 FMA + 64 ds_read_b128 per lane ----
      float acc[64];
      #pragma unroll
      for (int o = 0; o < 64; ++o) acc[o] = 0.f;

      #pragma unroll 4
      for (int b = 0; b < CB; ++b) {
        const float4 xa0 = *(const float4*)&Xa[b][4 * lane];
        const float4 xa1 = *(const float4*)&Xa[b][256 + 4 * lane];
        const float4 xb0 = *(const float4*)&Xb[b][4 * lane];
        const float4 xb1 = *(const float4*)&Xb[b][256 + 4 * lane];
        #pragma unroll
        for (int ji = 0; ji < 4; ++ji) {
          acc[b * 4 + ji] += dot4(wa[0][ji], xa0) + dot4(wa[1][ji], xa1)
                           + dot4(wb[0][ji], xb0) + dot4(wb[1][ji], xb1);
        }
      }

      // ---- binary-exchange reduction: output o lands on lane o, acc[0] ----
      #pragma unroll
      for (int d = 32; d >= 1; d >>= 1) {
        #pragma unroll
        for (int a = 0; a < d; ++a) {
          const bool  hi   = (lane & d) != 0;
          const float send = hi ? acc[a] : acc[a + d];
          const float keep = hi ? acc[a + d] : acc[a];
          acc[a] = keep + __shfl_xor(send, d);
        }
      }

      const float hn = tanhf(acc[0] + bias);
      const float hv = (t < len_o) ? hn : Xb[b_out][j_out];  // copy-forward
      hwr[(bbase + b_out) * HID + j_out] = hv;
    }

    // ---- device-wide barrier (monotone counter) ----
    __threadfence();   // release: drain h stores to coherence point
    __syncthreads();
    if (tid == 0) {
      __hip_atomic_fetch_add(cnt, 1u, __ATOMIC_RELAXED, __HIP_MEMORY_SCOPE_AGENT);
      const u32 target = (u32)(p + 1) * NWG;
      while (__hip_atomic_load(cnt, __ATOMIC_RELAXED, __HIP_MEMORY_SCOPE_AGENT) < target)
        __builtin_amdgcn_s_sleep(1);
    }
    __syncthreads();
    __threadfence();   // acquire: invalidate caches before reading fresh h
  }

  // ---- epilogue: h0 final parity 1 (last write p=511), h1 parity 0 (p=512)
  const float* h0f = h0buf + 1 * (BATCH * HID);
  const float* h1f = h1buf + 0 * (BATCH * HID);
  if (tid < 128) {
    const int idx = wg * 128 + tid;        // 256*128 = 32768 = B*H
    const int bb = idx >> 9, j = idx & 511;
    const float v0 = h0f[idx];
    const float v1 = h1f[idx];
    out[idx] = v1;                          // out = hidden[:, -1]
    out[32768 + bb * 1024 + j]       = v0;  // hidden[b][0][j]
    out[32768 + bb * 1024 + 512 + j] = v1;  // hidden[b][1][j]
  }
}

extern "C" void kernel_launch(void* const* d_in, const int* in_sizes, int n_in,
                              void* d_out, int out_size, void* d_ws, size_t ws_size,
                              hipStream_t stream) {
  (void)in_sizes; (void)n_in; (void)out_size; (void)ws_size;
  const int*   x       = (const int*)d_in[0];
  const int*   lengths = (const int*)d_in[1];
  const float* emb     = (const float*)d_in[2];
  const float* W_ih    = (const float*)d_in[3];
  const float* W_hh    = (const float*)d_in[4];
  const float* b_ih    = (const float*)d_in[5];
  const float* b_hh    = (const float*)d_in[6];
  float* out = (float*)d_out;

  float* h0buf = (float*)d_ws;                    // [2][64][512] fp32
  float* h1buf = h0buf + 2 * BATCH * HID;         // [2][64][512] fp32
  u32*   cnt   = (u32*)(h1buf + 2 * BATCH * HID); // barrier counter

  const size_t zero_bytes = (size_t)(4 * BATCH * HID) * sizeof(float) + 256;
  hipMemsetAsync(d_ws, 0, zero_bytes, stream);

  hipLaunchKernelGGL(rnn_persistent, dim3(NWG), dim3(NTHR), 0, stream,
                     x, lengths, emb, W_ih, W_hh, b_ih, b_hh, out,
                     h0buf, h1buf, cnt);
}

// Round 4
// 23937.209 us; speedup vs baseline: 2.3046x; 1.5984x over previous
//
#include <hip/hip_runtime.h>

// BaseRNN B=64,S=512,H=E=512,L=2 — persistent kernel, R4.
// R3 post-mortem: acc[64] was demoted to SCRATCH (variable-bound reduction
// loop -> dynamic indexing). Evidence: WRITE_SIZE 15.9GB (= per-phase wbl2
// of ~16MB scratch), VALUBusy 2.3%, VGPR=132 < 150 needed. R4:
//  - 16 accumulators/lane, all constant-indexed; sub-group loop unroll 1.
//  - exchange reduction d=32/16/8/4 (halving) + xor-add d=2,1; lane ends
//    with output (bi=(lane>>4)&3, ji=(lane>>2)&3), dup x4 over lane&3.
//  - h-writes staged to 16x16 LDS tile -> 64 coalesced float4 stores/WG.
//  - 4 independent 64-WG barrier domains (per batch-group; layers 0+1 of a
//    bg only ever share data with each other).

#define BATCH 64
#define SEQ   512
#define HID   512
#define NWG   256
#define NTHR  256
#define CB    16   // batches per WG
#define ROWS  16   // output rows per WG

typedef unsigned int u32;

__device__ __forceinline__ float dot4(const float4 a, const float4 b) {
  return a.x * b.x + a.y * b.y + a.z * b.z + a.w * b.w;
}

// exchange-reduction step: halve live slot count N, distance D
#define RSTEP(D, N)                                                   \
  {                                                                   \
    const bool hi = (lane & (D)) != 0;                                \
    _Pragma("unroll")                                                 \
    for (int a = 0; a < (N); ++a) {                                   \
      const float keep = hi ? v[a + (N)] : v[a];                      \
      const float send = hi ? v[a] : v[a + (N)];                      \
      v[a] = keep + __shfl_xor(send, (D));                            \
    }                                                                 \
  }

__global__ __launch_bounds__(NTHR, 1) void rnn_persistent(
    const int* __restrict__ x, const int* __restrict__ lengths,
    const float* __restrict__ emb,
    const float* __restrict__ W_ih, const float* __restrict__ W_hh,
    const float* __restrict__ b_ih, const float* __restrict__ b_hh,
    float* __restrict__ out,
    float* h0buf, float* h1buf, u32* cnt)
{
  __shared__ __align__(16) float Xa[CB][HID];   // 32KB emb row (l0) / h0_new (l1)
  __shared__ __align__(16) float Xb[CB][HID];   // 32KB own previous h
  __shared__ __align__(16) float Xout[CB][ROWS];// 1KB  output tile
  __shared__ int Lens[CB];

  const int wg    = blockIdx.x;
  const int tid   = threadIdx.x;
  const int layer = wg >> 7;
  const int wl    = wg & 127;
  const int bg    = wl >> 5;          // 0..3 batch-group = barrier domain
  const int rg    = wl & 31;          // 0..31 row-group
  const int bbase = bg * CB;
  const int jbase = rg * ROWS;
  const int tj    = tid >> 6;         // wave id -> j-quad
  const int lane  = tid & 63;

  // ---- weights in registers: 4 j x (2x4k) x 2 mats = 64 VGPRs ----
  float4 wa[2][4], wb[2][4];
  {
    const float* WA = W_ih + layer * (HID * HID);
    const float* WB = W_hh + layer * (HID * HID);
    #pragma unroll
    for (int ji = 0; ji < 4; ++ji) {
      const int j = jbase + tj * 4 + ji;
      #pragma unroll
      for (int i = 0; i < 2; ++i) {
        const int k = i * 256 + 4 * lane;
        wa[i][ji] = *(const float4*)&WA[j * HID + k];
        wb[i][ji] = *(const float4*)&WB[j * HID + k];
      }
    }
  }
  if (tid < CB) Lens[tid] = lengths[bbase + tid];

  const int   j_o    = tj * 4 + ((lane >> 2) & 3);  // local j this lane outputs
  const float bias_l = b_ih[layer * HID + jbase + j_o] +
                       b_hh[layer * HID + jbase + j_o];

  u32* myCnt = cnt + bg * 32;   // 128B-spaced counters, one per domain

  for (int p = 0; p <= SEQ; ++p) {
    const int rd = (p - 1) & 1;       // p=0 reads parity 1 (memset-zeroed)
    const int wr = p & 1;
    const bool active = (layer == 0) ? (p < SEQ) : (p >= 1);

    if (active) {
      const int t = (layer == 0) ? p : (p - 1);
      const float* hrd = (layer ? h1buf : h0buf) + rd * (BATCH * HID);
      float*       hwr = (layer ? h1buf : h0buf) + wr * (BATCH * HID);
      const float* ard = h0buf + rd * (BATCH * HID);  // layer1 input = h0(t)

      // ---- stage inputs: 2x 32KB, float4, coalesced ----
      #pragma unroll
      for (int i = 0; i < 8; ++i) {
        const int u = tid + NTHR * i;        // 0..2047
        const int r = u >> 7;                // batch row 0..15
        const int c = (u & 127) * 4;         // float4 column
        *(float4*)&Xb[r][c] = *(const float4*)&hrd[(bbase + r) * HID + c];
        if (layer == 0) {
          const int tok = x[(bbase + r) * SEQ + t];
          *(float4*)&Xa[r][c] = *(const float4*)&emb[tok * HID + c];
        } else {
          *(float4*)&Xa[r][c] = *(const float4*)&ard[(bbase + r) * HID + c];
        }
      }
      __syncthreads();

      // ---- compute 4 sub-groups of 4 batches; 16 accs, const-indexed ----
      #pragma unroll 1
      for (int g = 0; g < 4; ++g) {
        float v[16];
        #pragma unroll
        for (int o = 0; o < 16; ++o) v[o] = 0.f;

        #pragma unroll
        for (int bi = 0; bi < 4; ++bi) {
          const int b = g * 4 + bi;
          const float4 xa0 = *(const float4*)&Xa[b][4 * lane];
          const float4 xa1 = *(const float4*)&Xa[b][256 + 4 * lane];
          const float4 xb0 = *(const float4*)&Xb[b][4 * lane];
          const float4 xb1 = *(const float4*)&Xb[b][256 + 4 * lane];
          #pragma unroll
          for (int ji = 0; ji < 4; ++ji) {
            v[bi * 4 + ji] += dot4(wa[0][ji], xa0) + dot4(wa[1][ji], xa1)
                            + dot4(wb[0][ji], xb0) + dot4(wb[1][ji], xb1);
          }
        }

        RSTEP(32, 8)
        RSTEP(16, 4)
        RSTEP(8, 2)
        RSTEP(4, 1)
        v[0] += __shfl_xor(v[0], 2);
        v[0] += __shfl_xor(v[0], 1);
        // lane holds full sum for (b_o, j_o); lanes l,l^1,l^2,l^3 duplicate
        const int b_o = g * 4 + ((lane >> 4) & 3);
        const float hn = tanhf(v[0] + bias_l);
        const float hv = (t < Lens[b_o]) ? hn : Xb[b_o][jbase + j_o];
        if ((lane & 3) == 0) Xout[b_o][j_o] = hv;
      }
      __syncthreads();

      // ---- coalesced h write: 64 float4 = 16 rows x 64B ----
      if (tid < 64) {
        const int b = tid >> 2, c = (tid & 3) * 4;
        *(float4*)&hwr[(bbase + b) * HID + jbase + c] = *(const float4*)&Xout[b][c];
      }
    }

    // ---- domain barrier (64 WGs sharing this batch-group) ----
    __threadfence();   // release: writeback dirty L2 (now only h tiles)
    __syncthreads();
    if (tid == 0) {
      __hip_atomic_fetch_add(myCnt, 1u, __ATOMIC_RELAXED, __HIP_MEMORY_SCOPE_AGENT);
      const u32 target = (u32)(p + 1) * 64;
      while (__hip_atomic_load(myCnt, __ATOMIC_RELAXED, __HIP_MEMORY_SCOPE_AGENT) < target)
        __builtin_amdgcn_s_sleep(1);
    }
    __syncthreads();
    __threadfence();   // acquire: invalidate caches before reading fresh h
  }

  // ---- epilogue: own 16x16 slice. h0 final parity 1, h1 final parity 0 ----
  if (layer == 0 && tid < 64) {
    const float* h0f = h0buf + 1 * (BATCH * HID);
    const float* h1f = h1buf + 0 * (BATCH * HID);
    const int b = tid >> 2, c = (tid & 3) * 4;
    const int idx = (bbase + b) * HID + jbase + c;
    const float4 v0 = *(const float4*)&h0f[idx];
    const float4 v1 = *(const float4*)&h1f[idx];
    *(float4*)&out[(bbase + b) * HID + jbase + c] = v1;                       // out
    *(float4*)&out[32768 + (bbase + b) * 1024 + jbase + c] = v0;              // hidden l0
    *(float4*)&out[32768 + (bbase + b) * 1024 + 512 + jbase + c] = v1;        // hidden l1
  }
}

extern "C" void kernel_launch(void* const* d_in, const int* in_sizes, int n_in,
                              void* d_out, int out_size, void* d_ws, size_t ws_size,
                              hipStream_t stream) {
  (void)in_sizes; (void)n_in; (void)out_size; (void)ws_size;
  const int*   x       = (const int*)d_in[0];
  const int*   lengths = (const int*)d_in[1];
  const float* emb     = (const float*)d_in[2];
  const float* W_ih    = (const float*)d_in[3];
  const float* W_hh    = (const float*)d_in[4];
  const float* b_ih    = (const float*)d_in[5];
  const float* b_hh    = (const float*)d_in[6];
  float* out = (float*)d_out;

  float* h0buf = (float*)d_ws;                    // [2][64][512] fp32
  float* h1buf = h0buf + 2 * BATCH * HID;         // [2][64][512] fp32
  u32*   cnt   = (u32*)(h1buf + 2 * BATCH * HID); // 4 counters, 128B apart

  const size_t zero_bytes = (size_t)(4 * BATCH * HID) * sizeof(float) + 1024;
  hipMemsetAsync(d_ws, 0, zero_bytes, stream);

  hipLaunchKernelGGL(rnn_persistent, dim3(NWG), dim3(NTHR), 0, stream,
                     x, lengths, emb, W_ih, W_hh, b_ih, b_hh, out,
                     h0buf, h1buf, cnt);
}

// Round 5
// 4817.514 us; speedup vs baseline: 11.4509x; 4.9688x over previous
//
#include <hip/hip_runtime.h>

// BaseRNN B=64,S=512,H=E=512,L=2 — persistent kernel, R5.
// R4 post-mortem: spill fixed (WRITE 15.9GB->135MB) but 47us/phase remained,
// VALUBusy 5.6%. Residual = per-phase __threadfence pair: buffer_wbl2 +
// buffer_inv per WG per phase (64 L2-maintenance ops/XCD/phase, serialized)
// + L2 invalidation forcing emb/x refetch (FETCH 1.5MB/phase of read-only
// data). R5: NO cache maintenance at all. h exchanged via agent-scope
// RELAXED atomics (8B, global_load/store_dwordx2 sc1: bypass L2, coherent
// at L3). Release ordering = vmcnt(0) drain inside __syncthreads; acquire =
// free (sc1 loads can't see stale L2). emb/x/weights stay L2-cached across
// all phases. Barrier: 4 independent 64-WG domains (per batch-group).

#define BATCH 64
#define SEQ   512
#define HID   512
#define NWG   256
#define NTHR  256
#define CB    16   // batches per WG
#define ROWS  16   // output rows per WG
#define HROW  256  // doubles per h row (512 floats)

typedef unsigned int u32;

__device__ __forceinline__ float dot4(const float4 a, const float4 b) {
  return a.x * b.x + a.y * b.y + a.z * b.z + a.w * b.w;
}
__device__ __forceinline__ float2 ld_h(const double* p) {
  const double d = __hip_atomic_load(p, __ATOMIC_RELAXED, __HIP_MEMORY_SCOPE_AGENT);
  return __builtin_bit_cast(float2, d);
}
__device__ __forceinline__ void st_h(double* p, float2 v) {
  __hip_atomic_store(p, __builtin_bit_cast(double, v),
                     __ATOMIC_RELAXED, __HIP_MEMORY_SCOPE_AGENT);
}

// exchange-reduction step: halve live slot count N, distance D
#define RSTEP(D, N)                                                   \
  {                                                                   \
    const bool hi = (lane & (D)) != 0;                                \
    _Pragma("unroll")                                                 \
    for (int a = 0; a < (N); ++a) {                                   \
      const float keep = hi ? v[a + (N)] : v[a];                      \
      const float send = hi ? v[a] : v[a + (N)];                      \
      v[a] = keep + __shfl_xor(send, (D));                            \
    }                                                                 \
  }

__global__ __launch_bounds__(NTHR, 1) void rnn_persistent(
    const int* __restrict__ x, const int* __restrict__ lengths,
    const float* __restrict__ emb,
    const float* __restrict__ W_ih, const float* __restrict__ W_hh,
    const float* __restrict__ b_ih, const float* __restrict__ b_hh,
    float* __restrict__ out,
    double* h0d, double* h1d, u32* cnt)
{
  __shared__ __align__(16) float Xa[CB][HID];    // emb row (l0) / h0_new (l1)
  __shared__ __align__(16) float Xb[CB][HID];    // own previous h
  __shared__ __align__(16) float Xout[CB][ROWS]; // output tile
  __shared__ int Lens[CB];

  const int wg    = blockIdx.x;
  const int tid   = threadIdx.x;
  const int layer = wg >> 7;
  const int wl    = wg & 127;
  const int bg    = wl >> 5;          // 0..3 batch-group = barrier domain
  const int rg    = wl & 31;          // 0..31 row-group
  const int bbase = bg * CB;
  const int jbase = rg * ROWS;
  const int tj    = tid >> 6;         // wave id -> j-quad
  const int lane  = tid & 63;

  // ---- weights in registers: 4 j x (2x float4 k) x 2 mats = 64 VGPRs ----
  float4 wa[2][4], wb[2][4];
  {
    const float* WA = W_ih + layer * (HID * HID);
    const float* WB = W_hh + layer * (HID * HID);
    #pragma unroll
    for (int ji = 0; ji < 4; ++ji) {
      const int j = jbase + tj * 4 + ji;
      #pragma unroll
      for (int i = 0; i < 2; ++i) {
        const int k = i * 256 + 4 * lane;
        wa[i][ji] = *(const float4*)&WA[j * HID + k];
        wb[i][ji] = *(const float4*)&WB[j * HID + k];
      }
    }
  }
  if (tid < CB) Lens[tid] = lengths[bbase + tid];

  const int   j_o    = tj * 4 + ((lane >> 2) & 3);  // local j this lane outputs
  const float bias_l = b_ih[layer * HID + jbase + j_o] +
                       b_hh[layer * HID + jbase + j_o];

  u32* myCnt = cnt + bg * 32;   // 128B-spaced counters, one per domain

  for (int p = 0; p <= SEQ; ++p) {
    const int rd = (p - 1) & 1;       // p=0 reads parity 1 (memset-zeroed)
    const int wr = p & 1;
    const bool active = (layer == 0) ? (p < SEQ) : (p >= 1);

    if (active) {
      const int t = (layer == 0) ? p : (p - 1);
      const double* hrd = (layer ? h1d : h0d) + (size_t)rd * (BATCH * HROW);
      double*       hwr = (layer ? h1d : h0d) + (size_t)wr * (BATCH * HROW);
      const double* ard = h0d + (size_t)rd * (BATCH * HROW);  // l1 input = h0(t)

      // ---- stage own-h via sc1 atomics: 16 x 8B per thread, batched ----
      float2 tv[16];
      #pragma unroll
      for (int i = 0; i < 16; ++i) {
        const int u = tid + NTHR * i;          // double index 0..4095
        tv[i] = ld_h(&hrd[(size_t)(bbase + (u >> 8)) * HROW + (u & 255)]);
      }
      #pragma unroll
      for (int i = 0; i < 16; ++i) {
        const int u = tid + NTHR * i;
        *(float2*)&Xb[u >> 8][(u & 255) * 2] = tv[i];
      }
      if (layer == 0) {
        // emb gather: normal cached float4 loads (L2 stays warm — no inv)
        #pragma unroll
        for (int i = 0; i < 8; ++i) {
          const int u = tid + NTHR * i;        // 0..2047
          const int r = u >> 7, c = (u & 127) * 4;
          const int tok = x[(bbase + r) * SEQ + t];
          *(float4*)&Xa[r][c] = *(const float4*)&emb[(size_t)tok * HID + c];
        }
      } else {
        #pragma unroll
        for (int i = 0; i < 16; ++i) {
          const int u = tid + NTHR * i;
          tv[i] = ld_h(&ard[(size_t)(bbase + (u >> 8)) * HROW + (u & 255)]);
        }
        #pragma unroll
        for (int i = 0; i < 16; ++i) {
          const int u = tid + NTHR * i;
          *(float2*)&Xa[u >> 8][(u & 255) * 2] = tv[i];
        }
      }
      __syncthreads();

      // ---- compute 4 sub-groups of 4 batches; 16 accs, const-indexed ----
      #pragma unroll 1
      for (int g = 0; g < 4; ++g) {
        float v[16];
        #pragma unroll
        for (int o = 0; o < 16; ++o) v[o] = 0.f;

        #pragma unroll
        for (int bi = 0; bi < 4; ++bi) {
          const int b = g * 4 + bi;
          const float4 xa0 = *(const float4*)&Xa[b][4 * lane];
          const float4 xa1 = *(const float4*)&Xa[b][256 + 4 * lane];
          const float4 xb0 = *(const float4*)&Xb[b][4 * lane];
          const float4 xb1 = *(const float4*)&Xb[b][256 + 4 * lane];
          #pragma unroll
          for (int ji = 0; ji < 4; ++ji) {
            v[bi * 4 + ji] += dot4(wa[0][ji], xa0) + dot4(wa[1][ji], xa1)
                            + dot4(wb[0][ji], xb0) + dot4(wb[1][ji], xb1);
          }
        }

        RSTEP(32, 8)
        RSTEP(16, 4)
        RSTEP(8, 2)
        RSTEP(4, 1)
        v[0] += __shfl_xor(v[0], 2);
        v[0] += __shfl_xor(v[0], 1);
        const int b_o = g * 4 + ((lane >> 4) & 3);
        const float hn = tanhf(v[0] + bias_l);
        const float hv = (t < Lens[b_o]) ? hn : Xb[b_o][jbase + j_o];
        if ((lane & 3) == 0) Xout[b_o][j_o] = hv;
      }
      __syncthreads();

      // ---- h write: 128 x 8B sc1 stores (16 rows x 64B, coalesced) ----
      if (tid < 128) {
        const int b = tid >> 3, cp = tid & 7;
        const float2 v = *(const float2*)&Xout[b][cp * 2];
        st_h(&hwr[(size_t)(bbase + b) * HROW + (jbase >> 1) + cp], v);
      }
    }

    // ---- domain barrier; release = vmcnt drain in syncthreads, no wbl2/inv
    asm volatile("s_waitcnt vmcnt(0)" ::: "memory");
    __syncthreads();
    if (tid == 0) {
      __hip_atomic_fetch_add(myCnt, 1u, __ATOMIC_RELAXED, __HIP_MEMORY_SCOPE_AGENT);
      const u32 target = (u32)(p + 1) * 64;
      while (__hip_atomic_load(myCnt, __ATOMIC_RELAXED, __HIP_MEMORY_SCOPE_AGENT) < target)
        __builtin_amdgcn_s_sleep(1);
    }
    __syncthreads();
  }

  // ---- epilogue: own 16x16 slice; h0 final parity 1, h1 final parity 0 ----
  if (layer == 0 && tid < 128) {
    const double* h0f = h0d + 1 * (BATCH * HROW);
    const double* h1f = h1d + 0 * (BATCH * HROW);
    const int b = tid >> 3, cp = tid & 7;
    const size_t hidx = (size_t)(bbase + b) * HROW + (jbase >> 1) + cp;
    const float2 v0 = ld_h(&h0f[hidx]);
    const float2 v1 = ld_h(&h1f[hidx]);
    const int col = jbase + cp * 2;
    *(float2*)&out[(size_t)(bbase + b) * 512 + col] = v1;                 // out
    *(float2*)&out[32768 + (size_t)(bbase + b) * 1024 + col] = v0;        // hid l0
    *(float2*)&out[32768 + (size_t)(bbase + b) * 1024 + 512 + col] = v1;  // hid l1
  }
}

extern "C" void kernel_launch(void* const* d_in, const int* in_sizes, int n_in,
                              void* d_out, int out_size, void* d_ws, size_t ws_size,
                              hipStream_t stream) {
  (void)in_sizes; (void)n_in; (void)out_size; (void)ws_size;
  const int*   x       = (const int*)d_in[0];
  const int*   lengths = (const int*)d_in[1];
  const float* emb     = (const float*)d_in[2];
  const float* W_ih    = (const float*)d_in[3];
  const float* W_hh    = (const float*)d_in[4];
  const float* b_ih    = (const float*)d_in[5];
  const float* b_hh    = (const float*)d_in[6];
  float* out = (float*)d_out;

  double* h0d = (double*)d_ws;                    // [2][64][256] doubles
  double* h1d = h0d + 2 * BATCH * HROW;           // [2][64][256] doubles
  u32*    cnt = (u32*)(h1d + 2 * BATCH * HROW);   // 4 counters, 128B apart

  const size_t zero_bytes = (size_t)(4 * BATCH * HID) * sizeof(float) + 1024;
  hipMemsetAsync(d_ws, 0, zero_bytes, stream);

  hipLaunchKernelGGL(rnn_persistent, dim3(NWG), dim3(NTHR), 0, stream,
                     x, lengths, emb, W_ih, W_hh, b_ih, b_hh, out,
                     h0d, h1d, cnt);
}

// Round 7
// 4342.161 us; speedup vs baseline: 12.7045x; 1.1095x over previous
//
#include <hip/hip_runtime.h>

// BaseRNN B=64,S=512,H=E=512,L=2 — persistent kernel, R7.
// R6 failed at harness level (compile or hang) — it stacked 3 unproven
// constructs (s_getreg XCC_ID, sc0 inline-asm loads, raw L2 atomics).
// R7 recovers using ONLY R5-proven primitives (__hip_atomic sc1 exchange,
// agent counter barrier, s_waitcnt asm) + placement-free structural wins:
//  - 8 domains x 8 batches, ROWS=32, 16 row-groups/layer: halves sc1 read
//    duplication (12->6 MB/phase) and barrier arrivals (64->32/domain).
//  - emb/x t+1 prefetch issued inside the barrier window (after h-store
//    drain, before spin) -> emb latency overlaps the spin.
//  - per-domain early exit at P = max(lengths in domain) (sorted desc, all
//    32 WGs of a domain agree; nothing outside the domain reads its state).
//  - epilogue = per-WG self-reads from the fresh parity (no cross-WG deps).

#define BATCH 64
#define SEQ   512
#define HID   512
#define NTHR  256
#define CB    8     // batches per domain
#define ROWS  32    // output rows per WG
#define HROW  256   // doubles per h row (512 floats)

typedef unsigned int u32;

__device__ __forceinline__ float dot4(const float4 a, const float4 b) {
  return a.x * b.x + a.y * b.y + a.z * b.z + a.w * b.w;
}
__device__ __forceinline__ float2 ld_h(const double* p) {
  const double d = __hip_atomic_load(p, __ATOMIC_RELAXED, __HIP_MEMORY_SCOPE_AGENT);
  return __builtin_bit_cast(float2, d);
}
__device__ __forceinline__ void st_h(double* p, float2 v) {
  __hip_atomic_store(p, __builtin_bit_cast(double, v),
                     __ATOMIC_RELAXED, __HIP_MEMORY_SCOPE_AGENT);
}
#define WAIT_VM0() asm volatile("s_waitcnt vmcnt(0)" ::: "memory")

// exchange-reduction step: halve live slot count N, distance D
#define RSTEP(D, N)                                                   \
  {                                                                   \
    const bool hi = (lane & (D)) != 0;                                \
    _Pragma("unroll")                                                 \
    for (int a = 0; a < (N); ++a) {                                   \
      const float keep = hi ? v[a + (N)] : v[a];                      \
      const float send = hi ? v[a] : v[a + (N)];                      \
      v[a] = keep + __shfl_xor(send, (D));                            \
    }                                                                 \
  }

__global__ __launch_bounds__(NTHR, 1) void rnn_persistent(
    const int* __restrict__ x, const int* __restrict__ lengths,
    const float* __restrict__ emb,
    const float* __restrict__ W_ih, const float* __restrict__ W_hh,
    const float* __restrict__ b_ih, const float* __restrict__ b_hh,
    float* __restrict__ out,
    double* h0d, double* h1d, u32* ctrl)
{
  __shared__ __align__(16) float Xa[CB][HID];    // 16KB emb row (l0) / h0 cur (l1)
  __shared__ __align__(16) float Xb[CB][HID];    // 16KB own previous h
  __shared__ __align__(16) float Xout[CB][ROWS]; // 1KB  output tile
  __shared__ int Lens[CB];

  const int wg    = blockIdx.x;
  const int tid   = threadIdx.x;
  const int dom   = wg & 7;          // batch-group = barrier domain
  const int q     = wg >> 3;         // 0..31 within domain
  const int layer = q >> 4;
  const int rg    = q & 15;
  const int bbase = dom * CB;
  const int jbase = rg * ROWS;
  const int tj    = tid >> 6;        // wave -> j-octet
  const int lane  = tid & 63;

  u32* cnt = ctrl + dom * 32;        // 128B-spaced per-domain counters

  // ---- weights in registers: 8 j x (2 float4 k) x 2 mats = 128 VGPRs ----
  float4 wa[2][8], wb[2][8];
  {
    const float* WA = W_ih + layer * (HID * HID);
    const float* WB = W_hh + layer * (HID * HID);
    #pragma unroll
    for (int ji = 0; ji < 8; ++ji) {
      const int j = jbase + tj * 8 + ji;
      #pragma unroll
      for (int i = 0; i < 2; ++i) {
        const int k = i * 256 + 4 * lane;
        wa[i][ji] = *(const float4*)&WA[j * HID + k];
        wb[i][ji] = *(const float4*)&WB[j * HID + k];
      }
    }
  }
  if (tid < CB) Lens[tid] = lengths[bbase + tid];
  __syncthreads();
  int maxlen = Lens[0];
  #pragma unroll
  for (int i = 1; i < CB; ++i) maxlen = max(maxlen, Lens[i]);
  const int P = maxlen;              // last phase with real work (1..512)

  const int   j_o    = tj * 8 + ((lane >> 2) & 7);  // local j this lane outputs
  const float bias_l = b_ih[layer * HID + jbase + j_o] +
                       b_hh[layer * HID + jbase + j_o];

  // ---- initial emb prefetch (t=0) ----
  float4 pf[4];
  if (layer == 0) {
    #pragma unroll
    for (int i = 0; i < 4; ++i) {
      const int u = tid + NTHR * i;            // 0..1023 float4s over 8x512
      const int r = u >> 7, c = (u & 127) * 4;
      const int tok = x[(bbase + r) * SEQ];
      pf[i] = *(const float4*)&emb[(size_t)tok * HID + c];
    }
  }

  for (int p = 0; p <= P; ++p) {
    const int rd = (p - 1) & 1;       // p=0 reads parity 1 (memset-zeroed)
    const int wr = p & 1;
    const bool active = (layer == 0) ? (p < SEQ) : (p >= 1);

    if (active) {
      const int t = (layer == 0) ? p : (p - 1);
      const double* hrd = (layer ? h1d : h0d) + (size_t)rd * (BATCH * HROW);
      double*       hwr = (layer ? h1d : h0d) + (size_t)wr * (BATCH * HROW);
      const double* ard = h0d + (size_t)rd * (BATCH * HROW);  // l1 input = h0(t)

      // ---- stage own-h (and, for l1, h0) via sc1 atomics, batched ----
      float2 tv[8];
      #pragma unroll
      for (int i = 0; i < 8; ++i) {
        const int u = tid + NTHR * i;          // 0..2047 doubles over 8x256
        tv[i] = ld_h(&hrd[(size_t)(bbase + (u >> 8)) * HROW + (u & 255)]);
      }
      #pragma unroll
      for (int i = 0; i < 8; ++i) {
        const int u = tid + NTHR * i;
        *(float2*)&Xb[u >> 8][(u & 255) * 2] = tv[i];
      }
      if (layer == 1) {
        #pragma unroll
        for (int i = 0; i < 8; ++i) {
          const int u = tid + NTHR * i;
          tv[i] = ld_h(&ard[(size_t)(bbase + (u >> 8)) * HROW + (u & 255)]);
        }
        #pragma unroll
        for (int i = 0; i < 8; ++i) {
          const int u = tid + NTHR * i;
          *(float2*)&Xa[u >> 8][(u & 255) * 2] = tv[i];
        }
      } else {
        #pragma unroll
        for (int i = 0; i < 4; ++i) {          // Xa from prefetched emb rows
          const int u = tid + NTHR * i;
          *(float4*)&Xa[u >> 7][(u & 127) * 4] = pf[i];
        }
      }
      __syncthreads();

      // ---- compute: 4 groups of 2 batches x 8 j; 16 accs, const-indexed ----
      #pragma unroll 1
      for (int g = 0; g < 4; ++g) {
        float v[16];
        #pragma unroll
        for (int o = 0; o < 16; ++o) v[o] = 0.f;

        #pragma unroll
        for (int bi = 0; bi < 2; ++bi) {
          const int b = g * 2 + bi;
          const float4 xa0 = *(const float4*)&Xa[b][4 * lane];
          const float4 xa1 = *(const float4*)&Xa[b][256 + 4 * lane];
          const float4 xb0 = *(const float4*)&Xb[b][4 * lane];
          const float4 xb1 = *(const float4*)&Xb[b][256 + 4 * lane];
          #pragma unroll
          for (int ji = 0; ji < 8; ++ji) {
            v[bi * 8 + ji] += dot4(wa[0][ji], xa0) + dot4(wa[1][ji], xa1)
                            + dot4(wb[0][ji], xb0) + dot4(wb[1][ji], xb1);
          }
        }

        RSTEP(32, 8)   // lane bit5 -> bi
        RSTEP(16, 4)   // lane bit4 -> ji bit2
        RSTEP(8, 2)    // lane bit3 -> ji bit1
        RSTEP(4, 1)    // lane bit2 -> ji bit0
        v[0] += __shfl_xor(v[0], 2);
        v[0] += __shfl_xor(v[0], 1);
        const int b_o = g * 2 + (lane >> 5);
        const float hn = tanhf(v[0] + bias_l);
        const float hv = (t < Lens[b_o]) ? hn : Xb[b_o][jbase + j_o];
        if ((lane & 3) == 0) Xout[b_o][j_o] = hv;
      }
      __syncthreads();

      // ---- h write: 128 x 8B sc1 stores (8 rows x 128B, coalesced) ----
      if (tid < 128) {
        const int b = tid >> 4, cp = tid & 15;
        st_h(&hwr[(size_t)(bbase + b) * HROW + (jbase >> 1) + cp],
             *(const float2*)&Xout[b][cp * 2]);
      }
    }

    // ---- domain barrier; prefetch t+1 inside the spin window ----
    WAIT_VM0();                 // drain h stores only (pf not yet issued)
    __syncthreads();
    if (layer == 0 && p + 1 <= P && p + 1 < SEQ) {
      #pragma unroll
      for (int i = 0; i < 4; ++i) {
        const int u = tid + NTHR * i;
        const int r = u >> 7, c = (u & 127) * 4;
        const int tok = x[(bbase + r) * SEQ + (p + 1)];
        pf[i] = *(const float4*)&emb[(size_t)tok * HID + c];
      }
    }
    if (tid == 0) {
      __hip_atomic_fetch_add(cnt, 1u, __ATOMIC_RELAXED, __HIP_MEMORY_SCOPE_AGENT);
      const u32 target = (u32)(p + 1) * 32u;
      while (__hip_atomic_load(cnt, __ATOMIC_RELAXED, __HIP_MEMORY_SCOPE_AGENT) < target)
        __builtin_amdgcn_s_sleep(1);
    }
    __syncthreads();
  }

  // ---- epilogue: per-WG self-reads from the fresh parity ----
  const int fresh0 = ((P < SEQ) ? P : (SEQ - 1)) & 1;  // l0 last wrote here
  const int fresh1 = P & 1;                            // l1 last wrote here
  if (tid < 128) {
    const int b = tid >> 4, cp = tid & 15;
    const int col = jbase + cp * 2;
    if (layer == 0) {
      const float2 v0 = ld_h(&h0d[(size_t)fresh0 * (BATCH * HROW) +
                                  (size_t)(bbase + b) * HROW + (jbase >> 1) + cp]);
      *(float2*)&out[32768 + (size_t)(bbase + b) * 1024 + col] = v0;       // hid l0
    } else {
      const float2 v1 = ld_h(&h1d[(size_t)fresh1 * (BATCH * HROW) +
                                  (size_t)(bbase + b) * HROW + (jbase >> 1) + cp]);
      *(float2*)&out[(size_t)(bbase + b) * 512 + col] = v1;                // out
      *(float2*)&out[32768 + (size_t)(bbase + b) * 1024 + 512 + col] = v1; // hid l1
    }
  }
}

extern "C" void kernel_launch(void* const* d_in, const int* in_sizes, int n_in,
                              void* d_out, int out_size, void* d_ws, size_t ws_size,
                              hipStream_t stream) {
  (void)in_sizes; (void)n_in; (void)out_size; (void)ws_size;
  const int*   x       = (const int*)d_in[0];
  const int*   lengths = (const int*)d_in[1];
  const float* emb     = (const float*)d_in[2];
  const float* W_ih    = (const float*)d_in[3];
  const float* W_hh    = (const float*)d_in[4];
  const float* b_ih    = (const float*)d_in[5];
  const float* b_hh    = (const float*)d_in[6];
  float* out = (float*)d_out;

  double* h0d = (double*)d_ws;                    // [2][64][256] doubles
  double* h1d = h0d + 2 * BATCH * HROW;           // [2][64][256] doubles
  u32*    ctrl = (u32*)(h1d + 2 * BATCH * HROW);  // 8 counters, 128B apart

  const size_t zero_bytes = (size_t)(4 * BATCH * HID) * sizeof(float) + 2048;
  hipMemsetAsync(d_ws, 0, zero_bytes, stream);

  hipLaunchKernelGGL(rnn_persistent, dim3(256), dim3(NTHR), 0, stream,
                     x, lengths, emb, W_ih, W_hh, b_ih, b_hh, out,
                     h0d, h1d, ctrl);
}

// Round 8
// 3861.411 us; speedup vs baseline: 14.2862x; 1.1245x over previous
//
#include <hip/hip_runtime.h>

// BaseRNN B=64,S=512,H=E=512,L=2 — persistent kernel, R8.
// R7 post-mortem: phase ~8.5us didn't move when traffic+arrivals halved ->
// the floor is the SERIAL sc1 (L3) round-trip chain: drain -> L3 counter RMW
// -> spin detect -> sc1 staging (~700-900cyc each). R8 moves the chain into
// the domain's XCD-local L2 (~250cyc/hop):
//  - runtime coherence probe (plain store -> agent barrier -> first-touch
//    plain loads): cross-XCD writers leave dirty lines in a foreign L2, so
//    readers see memset-0 -> domain falls back to R7 sc1 path. Consensus
//    via agent-scope poison flag. No s_getreg, no new asm.
//  - fast path: h in a 513-slot RING (plain float4 ld/st; fresh addresses
//    every phase => provable L1 freshness, no cache maintenance). Barrier
//    via WORKGROUP-scope atomics (plain L2 global_atomic_add / cmpswap).
//    Spin = CAS-read idiom (immune to LLVM idempotent-RMW->load fold which
//    would hit stale L1 and hang).
//  - ring needs ~134.5MB ws, gated on ws_size at launch (else all-slow=R7).

#define BATCH 64
#define SEQ   512
#define HID   512
#define NTHR  256
#define CB    8     // batches per domain
#define ROWS  32    // output rows per WG
#define HROW  256   // doubles per h row (512 floats)
#define SLOT  (BATCH * HID)          // floats per ring slot (128KB)
#define NSLOT 513

typedef unsigned int u32;

__device__ __forceinline__ float dot4(const float4 a, const float4 b) {
  return a.x * b.x + a.y * b.y + a.z * b.z + a.w * b.w;
}
// ---- slow path (agent scope, L3) — proven R5/R7 primitives ----
__device__ __forceinline__ float2 ld_h(const double* p) {
  const double d = __hip_atomic_load(p, __ATOMIC_RELAXED, __HIP_MEMORY_SCOPE_AGENT);
  return __builtin_bit_cast(float2, d);
}
__device__ __forceinline__ void st_h(double* p, float2 v) {
  __hip_atomic_store(p, __builtin_bit_cast(double, v),
                     __ATOMIC_RELAXED, __HIP_MEMORY_SCOPE_AGENT);
}
#define WAIT_VM0() asm volatile("s_waitcnt vmcnt(0)" ::: "memory")

// exchange-reduction step: halve live slot count N, distance D
#define RSTEP(D, N)                                                   \
  {                                                                   \
    const bool hi = (lane & (D)) != 0;                                \
    _Pragma("unroll")                                                 \
    for (int a = 0; a < (N); ++a) {                                   \
      const float keep = hi ? v[a + (N)] : v[a];                      \
      const float send = hi ? v[a] : v[a + (N)];                      \
      v[a] = keep + __shfl_xor(send, (D));                            \
    }                                                                 \
  }

__global__ __launch_bounds__(NTHR, 1) void rnn_persistent(
    const int* __restrict__ x, const int* __restrict__ lengths,
    const float* __restrict__ emb,
    const float* __restrict__ W_ih, const float* __restrict__ W_hh,
    const float* __restrict__ b_ih, const float* __restrict__ b_hh,
    float* __restrict__ out,
    float* h0r, float* h1r, u32* ctrl, int fastAllowed)
{
  __shared__ __align__(16) float Xa[CB][HID];    // 16KB emb row (l0) / h0 cur (l1)
  __shared__ __align__(16) float Xb[CB][HID];    // 16KB own previous h
  __shared__ __align__(16) float Xout[CB][ROWS]; // 1KB  output tile
  __shared__ int Lens[CB];
  __shared__ int FastFlag;

  const int wg    = blockIdx.x;
  const int tid   = threadIdx.x;
  const int dom   = wg & 7;          // batch-group = barrier domain
  const int q     = wg >> 3;         // 0..31 within domain
  const int layer = q >> 4;
  const int rg    = q & 15;
  const int bbase = dom * CB;
  const int jbase = rg * ROWS;
  const int tj    = tid >> 6;        // wave -> j-octet
  const int lane  = tid & 63;

  u32* probe  = ctrl;                 // [0..255]   plain coherence slots
  u32* cInit  = ctrl + 256 + dom*32;  // agent init counter (128B apart)
  u32* poison = ctrl + 512 + dom*32;  // agent poison flag
  u32* cPhase = ctrl + 768 + dom*32;  // phase counter (L2-fast or L3-slow)

  // ---- weights in registers: 8 j x (2 float4 k) x 2 mats = 128 VGPRs ----
  float4 wa[2][8], wb[2][8];
  {
    const float* WA = W_ih + layer * (HID * HID);
    const float* WB = W_hh + layer * (HID * HID);
    #pragma unroll
    for (int ji = 0; ji < 8; ++ji) {
      const int j = jbase + tj * 8 + ji;
      #pragma unroll
      for (int i = 0; i < 2; ++i) {
        const int k = i * 256 + 4 * lane;
        wa[i][ji] = *(const float4*)&WA[j * HID + k];
        wb[i][ji] = *(const float4*)&WB[j * HID + k];
      }
    }
  }
  if (tid < CB) Lens[tid] = lengths[bbase + tid];
  __syncthreads();
  int maxlen = Lens[0];
  #pragma unroll
  for (int i = 1; i < CB; ++i) maxlen = max(maxlen, Lens[i]);
  const int P = maxlen;              // last phase with real work (1..512)

  const int   j_o    = tj * 8 + ((lane >> 2) & 7);
  const float bias_l = b_ih[layer * HID + jbase + j_o] +
                       b_hh[layer * HID + jbase + j_o];

  // ---- coherence probe: is this whole domain L2-coherent (same XCD)? ----
  if (fastAllowed) {
    if (tid == 0) probe[dom * 32 + q] = 0xC0FFEE00u + (u32)q;   // plain store
    WAIT_VM0();
    __syncthreads();
    if (tid == 0) {
      __hip_atomic_fetch_add(cInit, 1u, __ATOMIC_RELAXED, __HIP_MEMORY_SCOPE_AGENT);
      while (__hip_atomic_load(cInit, __ATOMIC_RELAXED, __HIP_MEMORY_SCOPE_AGENT) < 32u)
        __builtin_amdgcn_s_sleep(1);
    }
    __syncthreads();
    bool ok = true;
    if (tid < 32) ok = (probe[dom * 32 + tid] == 0xC0FFEE00u + (u32)tid); // plain, first-touch
    const unsigned long long m = __ballot(ok);
    if (tid == 0 && m != ~0ull)
      __hip_atomic_store(poison, 1u, __ATOMIC_RELAXED, __HIP_MEMORY_SCOPE_AGENT);
    __syncthreads();
    if (tid == 0) {
      __hip_atomic_fetch_add(cInit, 1u, __ATOMIC_RELAXED, __HIP_MEMORY_SCOPE_AGENT);
      while (__hip_atomic_load(cInit, __ATOMIC_RELAXED, __HIP_MEMORY_SCOPE_AGENT) < 64u)
        __builtin_amdgcn_s_sleep(1);
      FastFlag = (__hip_atomic_load(poison, __ATOMIC_RELAXED,
                                    __HIP_MEMORY_SCOPE_AGENT) == 0u) ? 1 : 0;
    }
    __syncthreads();
  } else {
    if (tid == 0) FastFlag = 0;
    __syncthreads();
  }
  const bool fast = (FastFlag != 0);

  // slow-path double views (ring slots 0,1 = parity buffers, memset-zeroed)
  double* h0d = (double*)h0r;
  double* h1d = (double*)h1r;

  // ---- initial emb prefetch (t=0) ----
  float4 pf[4];
  if (layer == 0) {
    #pragma unroll
    for (int i = 0; i < 4; ++i) {
      const int u = tid + NTHR * i;
      const int r = u >> 7, c = (u & 127) * 4;
      const int tok = x[(bbase + r) * SEQ];
      pf[i] = *(const float4*)&emb[(size_t)tok * HID + c];
    }
  }

  for (int p = 0; p <= P; ++p) {
    const bool active = (layer == 0) ? (p < SEQ) : (p >= 1);

    if (active) {
      const int t = (layer == 0) ? p : (p - 1);

      if (fast) {
        // ring slots: l0 reads h0[p], writes h0[p+1]; l1 reads h1[p-1] +
        // h0[p], writes h1[p]. All plain, first-touch each phase.
        const float* srcB = (layer == 0) ? (h0r + (size_t)p * SLOT)
                                         : (h1r + (size_t)(p - 1) * SLOT);
        float4 tb[4], ta[4];
        #pragma unroll
        for (int i = 0; i < 4; ++i) {
          const int u = tid + NTHR * i;
          tb[i] = *(const float4*)&srcB[(bbase + (u >> 7)) * HID + (u & 127) * 4];
        }
        if (layer == 1) {
          const float* srcA = h0r + (size_t)p * SLOT;
          #pragma unroll
          for (int i = 0; i < 4; ++i) {
            const int u = tid + NTHR * i;
            ta[i] = *(const float4*)&srcA[(bbase + (u >> 7)) * HID + (u & 127) * 4];
          }
        }
        #pragma unroll
        for (int i = 0; i < 4; ++i) {
          const int u = tid + NTHR * i;
          *(float4*)&Xb[u >> 7][(u & 127) * 4] = tb[i];
          if (layer == 1) *(float4*)&Xa[u >> 7][(u & 127) * 4] = ta[i];
        }
      } else {
        const int rd = (p - 1) & 1;
        const double* hrd = (layer ? h1d : h0d) + (size_t)rd * (BATCH * HROW);
        const double* ard = h0d + (size_t)rd * (BATCH * HROW);
        float2 tv[8];
        #pragma unroll
        for (int i = 0; i < 8; ++i) {
          const int u = tid + NTHR * i;
          tv[i] = ld_h(&hrd[(size_t)(bbase + (u >> 8)) * HROW + (u & 255)]);
        }
        #pragma unroll
        for (int i = 0; i < 8; ++i) {
          const int u = tid + NTHR * i;
          *(float2*)&Xb[u >> 8][(u & 255) * 2] = tv[i];
        }
        if (layer == 1) {
          #pragma unroll
          for (int i = 0; i < 8; ++i) {
            const int u = tid + NTHR * i;
            tv[i] = ld_h(&ard[(size_t)(bbase + (u >> 8)) * HROW + (u & 255)]);
          }
          #pragma unroll
          for (int i = 0; i < 8; ++i) {
            const int u = tid + NTHR * i;
            *(float2*)&Xa[u >> 8][(u & 255) * 2] = tv[i];
          }
        }
      }
      if (layer == 0) {    // Xa from prefetched emb rows
        #pragma unroll
        for (int i = 0; i < 4; ++i) {
          const int u = tid + NTHR * i;
          *(float4*)&Xa[u >> 7][(u & 127) * 4] = pf[i];
        }
      }
      __syncthreads();

      // ---- compute: 4 groups x (2 b x 8 j); 16 accs, const-indexed ----
      #pragma unroll 1
      for (int g = 0; g < 4; ++g) {
        float v[16];
        #pragma unroll
        for (int o = 0; o < 16; ++o) v[o] = 0.f;
        #pragma unroll
        for (int bi = 0; bi < 2; ++bi) {
          const int b = g * 2 + bi;
          const float4 xa0 = *(const float4*)&Xa[b][4 * lane];
          const float4 xa1 = *(const float4*)&Xa[b][256 + 4 * lane];
          const float4 xb0 = *(const float4*)&Xb[b][4 * lane];
          const float4 xb1 = *(const float4*)&Xb[b][256 + 4 * lane];
          #pragma unroll
          for (int ji = 0; ji < 8; ++ji) {
            v[bi * 8 + ji] += dot4(wa[0][ji], xa0) + dot4(wa[1][ji], xa1)
                            + dot4(wb[0][ji], xb0) + dot4(wb[1][ji], xb1);
          }
        }
        RSTEP(32, 8)
        RSTEP(16, 4)
        RSTEP(8, 2)
        RSTEP(4, 1)
        v[0] += __shfl_xor(v[0], 2);
        v[0] += __shfl_xor(v[0], 1);
        const int b_o = g * 2 + (lane >> 5);
        const float hn = tanhf(v[0] + bias_l);
        const float hv = (t < Lens[b_o]) ? hn : Xb[b_o][jbase + j_o];
        if ((lane & 3) == 0) Xout[b_o][j_o] = hv;
      }
      __syncthreads();

      // ---- h write ----
      if (fast) {
        float* dst = (layer == 0) ? (h0r + (size_t)(p + 1) * SLOT)
                                  : (h1r + (size_t)p * SLOT);
        if (tid < 64) {
          const int b = tid >> 3, c = (tid & 7) * 4;
          *(float4*)&dst[(bbase + b) * HID + jbase + c] = *(const float4*)&Xout[b][c];
        }
      } else {
        const int wr = p & 1;
        double* hwr = (layer ? h1d : h0d) + (size_t)wr * (BATCH * HROW);
        if (tid < 128) {
          const int b = tid >> 4, cp = tid & 15;
          st_h(&hwr[(size_t)(bbase + b) * HROW + (jbase >> 1) + cp],
               *(const float2*)&Xout[b][cp * 2]);
        }
      }
    }

    // ---- domain barrier; emb prefetch for t+1 inside the spin window ----
    WAIT_VM0();
    __syncthreads();
    if (layer == 0 && p + 1 <= P && p + 1 < SEQ) {
      #pragma unroll
      for (int i = 0; i < 4; ++i) {
        const int u = tid + NTHR * i;
        const int r = u >> 7, c = (u & 127) * 4;
        const int tok = x[(bbase + r) * SEQ + (p + 1)];
        pf[i] = *(const float4*)&emb[(size_t)tok * HID + c];
      }
    }
    if (tid == 0) {
      const u32 target = (u32)(p + 1) * 32u;
      if (fast) {
        __hip_atomic_fetch_add(cPhase, 1u, __ATOMIC_RELAXED, __HIP_MEMORY_SCOPE_WORKGROUP);
        u32 seen = 0;
        while (seen < target) {           // CAS-read: always an L2 RMW
          u32 e = seen;
          u32 d = e;
          asm volatile("" : "+v"(d));     // opaque copy: block any cmpxchg fold
          __hip_atomic_compare_exchange_strong(cPhase, &e, d,
              __ATOMIC_RELAXED, __ATOMIC_RELAXED, __HIP_MEMORY_SCOPE_WORKGROUP);
          seen = e;
          if (seen < target) __builtin_amdgcn_s_sleep(1);
        }
      } else {
        __hip_atomic_fetch_add(cPhase, 1u, __ATOMIC_RELAXED, __HIP_MEMORY_SCOPE_AGENT);
        while (__hip_atomic_load(cPhase, __ATOMIC_RELAXED, __HIP_MEMORY_SCOPE_AGENT) < target)
          __builtin_amdgcn_s_sleep(1);
      }
    }
    __syncthreads();
  }

  // ---- epilogue: per-WG self-reads of final slots ----
  const int lastT0 = (P < SEQ) ? P : (SEQ - 1);   // l0's last written t
  if (fast) {
    if (tid < 64) {
      const int b = tid >> 3, c = (tid & 7) * 4;
      const int idx = (bbase + b) * HID + jbase + c;
      if (layer == 0) {
        const float4 v0 = *(const float4*)&h0r[(size_t)(lastT0 + 1) * SLOT + idx];
        *(float4*)&out[32768 + (size_t)(bbase + b) * 1024 + jbase + c] = v0;
      } else {
        const float4 v1 = *(const float4*)&h1r[(size_t)P * SLOT + idx];
        *(float4*)&out[(size_t)(bbase + b) * 512 + jbase + c] = v1;
        *(float4*)&out[32768 + (size_t)(bbase + b) * 1024 + 512 + jbase + c] = v1;
      }
    }
  } else {
    const int fresh0 = lastT0 & 1;
    const int fresh1 = P & 1;
    if (tid < 128) {
      const int b = tid >> 4, cp = tid & 15;
      const int col = jbase + cp * 2;
      if (layer == 0) {
        const float2 v0 = ld_h(&h0d[(size_t)fresh0 * (BATCH * HROW) +
                                    (size_t)(bbase + b) * HROW + (jbase >> 1) + cp]);
        *(float2*)&out[32768 + (size_t)(bbase + b) * 1024 + col] = v0;
      } else {
        const float2 v1 = ld_h(&h1d[(size_t)fresh1 * (BATCH * HROW) +
                                    (size_t)(bbase + b) * HROW + (jbase >> 1) + cp]);
        *(float2*)&out[(size_t)(bbase + b) * 512 + col] = v1;
        *(float2*)&out[32768 + (size_t)(bbase + b) * 1024 + 512 + col] = v1;
      }
    }
  }
}

extern "C" void kernel_launch(void* const* d_in, const int* in_sizes, int n_in,
                              void* d_out, int out_size, void* d_ws, size_t ws_size,
                              hipStream_t stream) {
  (void)in_sizes; (void)n_in; (void)out_size;
  const int*   x       = (const int*)d_in[0];
  const int*   lengths = (const int*)d_in[1];
  const float* emb     = (const float*)d_in[2];
  const float* W_ih    = (const float*)d_in[3];
  const float* W_hh    = (const float*)d_in[4];
  const float* b_ih    = (const float*)d_in[5];
  const float* b_hh    = (const float*)d_in[6];
  float* out = (float*)d_out;

  const size_t slotB    = (size_t)SLOT * sizeof(float);          // 128KB
  const size_t ringB    = (size_t)NSLOT * slotB;                 // 65.7MB
  const int    ringOK   = (ws_size >= 2 * ringB + 8192) ? 1 : 0;
  const size_t layerSpan = ringOK ? (size_t)NSLOT * SLOT : 2 * (size_t)SLOT;

  float* h0r  = (float*)d_ws;
  float* h1r  = h0r + layerSpan;
  u32*   ctrl = (u32*)(h1r + layerSpan);

  // zero ring slots 0,1 of both layers (h(-1)=0 for fast AND slow parity
  // buffers) + control page. d_ws is re-poisoned 0xAA before every launch.
  hipMemsetAsync(h0r, 0, 2 * slotB, stream);
  hipMemsetAsync(h1r, 0, 2 * slotB, stream);
  hipMemsetAsync(ctrl, 0, 4096, stream);

  hipLaunchKernelGGL(rnn_persistent, dim3(256), dim3(NTHR), 0, stream,
                     x, lengths, emb, W_ih, W_hh, b_ih, b_hh, out,
                     h0r, h1r, ctrl, ringOK);
}

// Round 9
// 3690.783 us; speedup vs baseline: 14.9467x; 1.0462x over previous
//
#include <hip/hip_runtime.h>

// BaseRNN B=64,S=512,H=E=512,L=2 — persistent kernel, R9.
// R8 post-mortem: fast path ran (WRITE 71->83MB ring signature) but phase
// stuck at 7.5us — the barrier poll was 32 CAS RMWs hammering ONE L2 line
// (serializing ~200cyc each). R9:
//  - leader/follower barrier: 16 arrivals -> per-LAYER counter; only the
//    leader polls it; release via per-WG flag words on DISTINCT 64B lines,
//    each follower CAS-polls its own line (uncontended). No sleeps.
//  - layer decoupling over the 513-slot ring (no WAR hazards): l0 never
//    waits for l1; l1 waits c0>=16(p+1) (pre-satisfied when l0 runs ahead)
//    + its own 16-WG chain.
//  - compute ILP: unroll 2 groups (2 interleaved shfl chains, const-indexed
//    accs); last 2 shfl stages replaced by 4-partial LDS sum in a 64-thread
//    finalize (tanh/mask/store there too).
// Probe/consensus + slow sc1 fallback identical to R8 (proven).

#define BATCH 64
#define SEQ   512
#define HID   512
#define NTHR  256
#define CB    8     // batches per domain
#define ROWS  32    // output rows per WG
#define HROW  256   // doubles per h row
#define SLOT  (BATCH * HID)
#define NSLOT 513

typedef unsigned int u32;

__device__ __forceinline__ float dot4(const float4 a, const float4 b) {
  return a.x * b.x + a.y * b.y + a.z * b.z + a.w * b.w;
}
__device__ __forceinline__ float2 ld_h(const double* p) {
  const double d = __hip_atomic_load(p, __ATOMIC_RELAXED, __HIP_MEMORY_SCOPE_AGENT);
  return __builtin_bit_cast(float2, d);
}
__device__ __forceinline__ void st_h(double* p, float2 v) {
  __hip_atomic_store(p, __builtin_bit_cast(double, v),
                     __ATOMIC_RELAXED, __HIP_MEMORY_SCOPE_AGENT);
}
#define WAIT_VM0() asm volatile("s_waitcnt vmcnt(0)" ::: "memory")

// L2-executed read (never folds to a plain load): CAS(0,0) returns current.
__device__ __forceinline__ u32 cas_read(u32* p) {
  u32 e = 0, d = 0;
  asm volatile("" : "+v"(d));
  __hip_atomic_compare_exchange_strong(p, &e, d, __ATOMIC_RELAXED,
                                       __ATOMIC_RELAXED, __HIP_MEMORY_SCOPE_WORKGROUP);
  return e;
}

#define RSTEP(D, N)                                                   \
  {                                                                   \
    const bool hi = (lane & (D)) != 0;                                \
    _Pragma("unroll")                                                 \
    for (int a = 0; a < (N); ++a) {                                   \
      const float keep = hi ? v[a + (N)] : v[a];                      \
      const float send = hi ? v[a] : v[a + (N)];                      \
      v[a] = keep + __shfl_xor(send, (D));                            \
    }                                                                 \
  }

__global__ __launch_bounds__(NTHR, 1) void rnn_persistent(
    const int* __restrict__ x, const int* __restrict__ lengths,
    const float* __restrict__ emb,
    const float* __restrict__ W_ih, const float* __restrict__ W_hh,
    const float* __restrict__ b_ih, const float* __restrict__ b_hh,
    float* __restrict__ out,
    float* h0r, float* h1r, u32* ctrl, int fastAllowed)
{
  __shared__ __align__(16) float Xa[CB][HID];        // 16KB
  __shared__ __align__(16) float Xb[CB][HID];        // 16KB
  __shared__ __align__(16) float Xpart[CB][ROWS][4]; // 4KB partial sums
  __shared__ int Lens[CB];
  __shared__ int FastFlag;

  const int wg    = blockIdx.x;
  const int tid   = threadIdx.x;
  const int dom   = wg & 7;
  const int q     = wg >> 3;
  const int layer = q >> 4;
  const int rg    = q & 15;
  const int bbase = dom * CB;
  const int jbase = rg * ROWS;
  const int tj    = tid >> 6;
  const int lane  = tid & 63;

  u32* probe  = ctrl;
  u32* cInit  = ctrl + 256 + dom * 32;
  u32* poison = ctrl + 512 + dom * 32;
  u32* cL     = ctrl + 1024 + (dom * 2 + layer) * 16;  // own-layer counter
  u32* cL0    = ctrl + 1024 + (dom * 2) * 16;          // layer0 / slow combined
  u32* fBase  = ctrl + 2048 + ((dom * 2 + layer) * 16) * 16;  // flags, 64B apart
  u32* myFlag = fBase + rg * 16;

  // ---- weights in registers: 8 j x (2 float4 k) x 2 mats = 128 VGPRs ----
  float4 wa[2][8], wb[2][8];
  {
    const float* WA = W_ih + layer * (HID * HID);
    const float* WB = W_hh + layer * (HID * HID);
    #pragma unroll
    for (int ji = 0; ji < 8; ++ji) {
      const int j = jbase + tj * 8 + ji;
      #pragma unroll
      for (int i = 0; i < 2; ++i) {
        const int k = i * 256 + 4 * lane;
        wa[i][ji] = *(const float4*)&WA[j * HID + k];
        wb[i][ji] = *(const float4*)&WB[j * HID + k];
      }
    }
  }
  if (tid < CB) Lens[tid] = lengths[bbase + tid];
  __syncthreads();
  int maxlen = Lens[0];
  #pragma unroll
  for (int i = 1; i < CB; ++i) maxlen = max(maxlen, Lens[i]);
  const int P = maxlen;

  // finalize-thread constants (tid<64): 4 j-columns each
  float4 bias4 = make_float4(0.f, 0.f, 0.f, 0.f);
  if (tid < 64) {
    const int jq = jbase + (tid & 7) * 4;
    bias4.x = b_ih[layer * HID + jq + 0] + b_hh[layer * HID + jq + 0];
    bias4.y = b_ih[layer * HID + jq + 1] + b_hh[layer * HID + jq + 1];
    bias4.z = b_ih[layer * HID + jq + 2] + b_hh[layer * HID + jq + 2];
    bias4.w = b_ih[layer * HID + jq + 3] + b_hh[layer * HID + jq + 3];
  }

  // ---- coherence probe (verbatim R8, proven) ----
  if (fastAllowed) {
    if (tid == 0) probe[dom * 32 + q] = 0xC0FFEE00u + (u32)q;
    WAIT_VM0();
    __syncthreads();
    if (tid == 0) {
      __hip_atomic_fetch_add(cInit, 1u, __ATOMIC_RELAXED, __HIP_MEMORY_SCOPE_AGENT);
      while (__hip_atomic_load(cInit, __ATOMIC_RELAXED, __HIP_MEMORY_SCOPE_AGENT) < 32u)
        __builtin_amdgcn_s_sleep(1);
    }
    __syncthreads();
    bool ok = true;
    if (tid < 32) ok = (probe[dom * 32 + tid] == 0xC0FFEE00u + (u32)tid);
    const unsigned long long m = __ballot(ok);
    if (tid == 0 && m != ~0ull)
      __hip_atomic_store(poison, 1u, __ATOMIC_RELAXED, __HIP_MEMORY_SCOPE_AGENT);
    __syncthreads();
    if (tid == 0) {
      __hip_atomic_fetch_add(cInit, 1u, __ATOMIC_RELAXED, __HIP_MEMORY_SCOPE_AGENT);
      while (__hip_atomic_load(cInit, __ATOMIC_RELAXED, __HIP_MEMORY_SCOPE_AGENT) < 64u)
        __builtin_amdgcn_s_sleep(1);
      FastFlag = (__hip_atomic_load(poison, __ATOMIC_RELAXED,
                                    __HIP_MEMORY_SCOPE_AGENT) == 0u) ? 1 : 0;
    }
    __syncthreads();
  } else {
    if (tid == 0) FastFlag = 0;
    __syncthreads();
  }
  const bool fast = (FastFlag != 0);

  double* h0d = (double*)h0r;   // slow-path parity views (slots 0,1 zeroed)
  double* h1d = (double*)h1r;

  // ---- initial emb prefetch (t=0) ----
  float4 pf[4];
  if (layer == 0) {
    #pragma unroll
    for (int i = 0; i < 4; ++i) {
      const int u = tid + NTHR * i;
      const int r = u >> 7, c = (u & 127) * 4;
      const int tok = x[(bbase + r) * SEQ];
      pf[i] = *(const float4*)&emb[(size_t)tok * HID + c];
    }
  }

  for (int p = 0; p <= P; ++p) {
    const bool active = (layer == 0) ? (p < SEQ) : (p >= 1);

    if (active) {
      const int t = (layer == 0) ? p : (p - 1);

      // ---- stage inputs ----
      if (fast) {
        const float* srcB = (layer == 0) ? (h0r + (size_t)p * SLOT)
                                         : (h1r + (size_t)(p - 1) * SLOT);
        float4 tb[4], ta[4];
        #pragma unroll
        for (int i = 0; i < 4; ++i) {
          const int u = tid + NTHR * i;
          tb[i] = *(const float4*)&srcB[(bbase + (u >> 7)) * HID + (u & 127) * 4];
        }
        if (layer == 1) {
          const float* srcA = h0r + (size_t)p * SLOT;
          #pragma unroll
          for (int i = 0; i < 4; ++i) {
            const int u = tid + NTHR * i;
            ta[i] = *(const float4*)&srcA[(bbase + (u >> 7)) * HID + (u & 127) * 4];
          }
        }
        #pragma unroll
        for (int i = 0; i < 4; ++i) {
          const int u = tid + NTHR * i;
          *(float4*)&Xb[u >> 7][(u & 127) * 4] = tb[i];
          if (layer == 1) *(float4*)&Xa[u >> 7][(u & 127) * 4] = ta[i];
        }
      } else {
        const int rd = (p - 1) & 1;
        const double* hrd = (layer ? h1d : h0d) + (size_t)rd * (BATCH * HROW);
        const double* ard = h0d + (size_t)rd * (BATCH * HROW);
        float2 tv[8];
        #pragma unroll
        for (int i = 0; i < 8; ++i) {
          const int u = tid + NTHR * i;
          tv[i] = ld_h(&hrd[(size_t)(bbase + (u >> 8)) * HROW + (u & 255)]);
        }
        #pragma unroll
        for (int i = 0; i < 8; ++i) {
          const int u = tid + NTHR * i;
          *(float2*)&Xb[u >> 8][(u & 255) * 2] = tv[i];
        }
        if (layer == 1) {
          #pragma unroll
          for (int i = 0; i < 8; ++i) {
            const int u = tid + NTHR * i;
            tv[i] = ld_h(&ard[(size_t)(bbase + (u >> 8)) * HROW + (u & 255)]);
          }
          #pragma unroll
          for (int i = 0; i < 8; ++i) {
            const int u = tid + NTHR * i;
            *(float2*)&Xa[u >> 8][(u & 255) * 2] = tv[i];
          }
        }
      }
      if (layer == 0) {
        #pragma unroll
        for (int i = 0; i < 4; ++i) {
          const int u = tid + NTHR * i;
          *(float4*)&Xa[u >> 7][(u & 127) * 4] = pf[i];
        }
      }
      __syncthreads();

      // ---- compute: 4 groups, unroll 2 (interleaved reduction chains) ----
      #pragma unroll 2
      for (int g = 0; g < 4; ++g) {
        float v[16];
        #pragma unroll
        for (int o = 0; o < 16; ++o) v[o] = 0.f;
        #pragma unroll
        for (int bi = 0; bi < 2; ++bi) {
          const int b = g * 2 + bi;
          const float4 xa0 = *(const float4*)&Xa[b][4 * lane];
          const float4 xa1 = *(const float4*)&Xa[b][256 + 4 * lane];
          const float4 xb0 = *(const float4*)&Xb[b][4 * lane];
          const float4 xb1 = *(const float4*)&Xb[b][256 + 4 * lane];
          #pragma unroll
          for (int ji = 0; ji < 8; ++ji) {
            v[bi * 8 + ji] += dot4(wa[0][ji], xa0) + dot4(wa[1][ji], xa1)
                            + dot4(wb[0][ji], xb0) + dot4(wb[1][ji], xb1);
          }
        }
        RSTEP(32, 8)
        RSTEP(16, 4)
        RSTEP(8, 2)
        RSTEP(4, 1)
        // v[0] = partial over lane bits {0,1}; 4 partials per output
        const int b_o = g * 2 + (lane >> 5);
        const int j_o = tj * 8 + ((lane >> 2) & 7);
        Xpart[b_o][j_o][lane & 3] = v[0];
      }
      __syncthreads();

      // ---- finalize: 64 threads sum 4 partials, tanh, mask, store ----
      if (tid < 64) {
        const int b = tid >> 3, jq = (tid & 7) * 4;
        const float4 p0 = *(const float4*)&Xpart[b][jq + 0][0];
        const float4 p1 = *(const float4*)&Xpart[b][jq + 1][0];
        const float4 p2 = *(const float4*)&Xpart[b][jq + 2][0];
        const float4 p3 = *(const float4*)&Xpart[b][jq + 3][0];
        const float4 hb = *(const float4*)&Xb[b][jbase + jq];
        const bool live = (t < Lens[b]);
        float4 r;
        r.x = live ? tanhf(p0.x + p0.y + p0.z + p0.w + bias4.x) : hb.x;
        r.y = live ? tanhf(p1.x + p1.y + p1.z + p1.w + bias4.y) : hb.y;
        r.z = live ? tanhf(p2.x + p2.y + p2.z + p2.w + bias4.z) : hb.z;
        r.w = live ? tanhf(p3.x + p3.y + p3.z + p3.w + bias4.w) : hb.w;
        if (fast) {
          float* dst = (layer == 0) ? (h0r + (size_t)(p + 1) * SLOT)
                                    : (h1r + (size_t)p * SLOT);
          *(float4*)&dst[(bbase + b) * HID + jbase + jq] = r;
        } else {
          const int wr = p & 1;
          double* hwr = (layer ? h1d : h0d) + (size_t)wr * (BATCH * HROW);
          st_h(&hwr[(size_t)(bbase + b) * HROW + ((jbase + jq) >> 1)],
               make_float2(r.x, r.y));
          st_h(&hwr[(size_t)(bbase + b) * HROW + ((jbase + jq) >> 1) + 1],
               make_float2(r.z, r.w));
        }
      }
    }

    // ---- barrier ----
    WAIT_VM0();               // h stores drained before arrival
    __syncthreads();
    if (layer == 0 && p + 1 <= P && p + 1 < SEQ) {   // prefetch overlaps wait
      #pragma unroll
      for (int i = 0; i < 4; ++i) {
        const int u = tid + NTHR * i;
        const int r = u >> 7, c = (u & 127) * 4;
        const int tok = x[(bbase + r) * SEQ + (p + 1)];
        pf[i] = *(const float4*)&emb[(size_t)tok * HID + c];
      }
    }
    if (tid == 0) {
      if (fast) {
        __hip_atomic_fetch_add(cL, 1u, __ATOMIC_RELAXED, __HIP_MEMORY_SCOPE_WORKGROUP);
        const u32 tgt = (u32)(p + 1) * 16u;
        if (rg == 0) {                       // leader: sole poller of counters
          while (cas_read(cL) < tgt) {}
          if (layer == 1) { while (cas_read(cL0) < tgt) {} }
          #pragma unroll 1
          for (int r = 1; r < 16; ++r)       // release: distinct 64B lines
            __hip_atomic_store(fBase + r * 16, (u32)(p + 1),
                               __ATOMIC_RELAXED, __HIP_MEMORY_SCOPE_WORKGROUP);
        } else {                             // follower: own line only
          while (cas_read(myFlag) < (u32)(p + 1)) {}
        }
      } else {
        __hip_atomic_fetch_add(cL0, 1u, __ATOMIC_RELAXED, __HIP_MEMORY_SCOPE_AGENT);
        const u32 tgt = (u32)(p + 1) * 32u;
        while (__hip_atomic_load(cL0, __ATOMIC_RELAXED, __HIP_MEMORY_SCOPE_AGENT) < tgt)
          __builtin_amdgcn_s_sleep(1);
      }
    }
    __syncthreads();
  }

  // ---- epilogue: per-WG self-reads of final slots ----
  const int lastT0 = (P < SEQ) ? P : (SEQ - 1);
  if (fast) {
    if (tid < 64) {
      const int b = tid >> 3, c = (tid & 7) * 4;
      const int idx = (bbase + b) * HID + jbase + c;
      if (layer == 0) {
        const float4 v0 = *(const float4*)&h0r[(size_t)(lastT0 + 1) * SLOT + idx];
        *(float4*)&out[32768 + (size_t)(bbase + b) * 1024 + jbase + c] = v0;
      } else {
        const float4 v1 = *(const float4*)&h1r[(size_t)P * SLOT + idx];
        *(float4*)&out[(size_t)(bbase + b) * 512 + jbase + c] = v1;
        *(float4*)&out[32768 + (size_t)(bbase + b) * 1024 + 512 + jbase + c] = v1;
      }
    }
  } else {
    const int fresh0 = lastT0 & 1;
    const int fresh1 = P & 1;
    if (tid < 128) {
      const int b = tid >> 4, cp = tid & 15;
      const int col = jbase + cp * 2;
      if (layer == 0) {
        const float2 v0 = ld_h(&h0d[(size_t)fresh0 * (BATCH * HROW) +
                                    (size_t)(bbase + b) * HROW + (jbase >> 1) + cp]);
        *(float2*)&out[32768 + (size_t)(bbase + b) * 1024 + col] = v0;
      } else {
        const float2 v1 = ld_h(&h1d[(size_t)fresh1 * (BATCH * HROW) +
                                    (size_t)(bbase + b) * HROW + (jbase >> 1) + cp]);
        *(float2*)&out[(size_t)(bbase + b) * 512 + col] = v1;
        *(float2*)&out[32768 + (size_t)(bbase + b) * 1024 + 512 + col] = v1;
      }
    }
  }
}

extern "C" void kernel_launch(void* const* d_in, const int* in_sizes, int n_in,
                              void* d_out, int out_size, void* d_ws, size_t ws_size,
                              hipStream_t stream) {
  (void)in_sizes; (void)n_in; (void)out_size;
  const int*   x       = (const int*)d_in[0];
  const int*   lengths = (const int*)d_in[1];
  const float* emb     = (const float*)d_in[2];
  const float* W_ih    = (const float*)d_in[3];
  const float* W_hh    = (const float*)d_in[4];
  const float* b_ih    = (const float*)d_in[5];
  const float* b_hh    = (const float*)d_in[6];
  float* out = (float*)d_out;

  const size_t slotB  = (size_t)SLOT * sizeof(float);          // 128KB
  const size_t ringB  = (size_t)NSLOT * slotB;                 // 65.7MB
  const int    ringOK = (ws_size >= 2 * ringB + 65536) ? 1 : 0;
  const size_t layerSpan = ringOK ? (size_t)NSLOT * SLOT : 2 * (size_t)SLOT;

  float* h0r  = (float*)d_ws;
  float* h1r  = h0r + layerSpan;
  u32*   ctrl = (u32*)(h1r + layerSpan);

  hipMemsetAsync(h0r, 0, 2 * slotB, stream);   // h(-1)=0 (fast slot0 / slow parity)
  hipMemsetAsync(h1r, 0, 2 * slotB, stream);
  hipMemsetAsync(ctrl, 0, 32768, stream);      // probe+counters+flags

  hipLaunchKernelGGL(rnn_persistent, dim3(256), dim3(NTHR), 0, stream,
                     x, lengths, emb, W_ih, W_hh, b_ih, b_hh, out,
                     h0r, h1r, ctrl, ringOK);
}

// Round 10
// 2982.446 us; speedup vs baseline: 18.4965x; 1.2375x over previous
//
#include <hip/hip_runtime.h>

// BaseRNN B=64,S=512,H=E=512,L=2 — persistent kernel, R10.
// R9 post-mortem: phase 7.2us = 0.9us VALU + ~6.3us serial latency chain;
// leader/follower only bought 4% because the chain LENGTH (drain, arrive-RMW,
// detect, release, load = 5-6 dependent round trips) is the floor, not the
// per-hop venue (L2 vs L3). R10 removes hops:
//  - arrival = ONE sc1 STORE of phase# to a per-WG flag line (no RMW);
//    detect = 32 lanes poll all peer flags in parallel + ballot (no leader,
//    no release broadcast). Chain: drain -> store -> detect -> load.
//  - layer decoupling: l0 polls only l0 peers; l1 polls flag0>=p+1 &
//    flag1>=p. l0 free-runs over the 513-slot ring -> l1 (critical chain)
//    finds l0 data pre-published.
//  - epilogue fused into last-phase finalize (own tile = own output);
//    fast tanh ((1-e)*rcp(1+e), e=exp(-2|x|)); group-skip for frozen
//    batch-pairs (dom-0 tail at ~1/4 compute); emb prefetch kept.
//  - NO probe, NO fast/slow dual path, NO placement assumption: one proven
//    agent-scope (sc1) protocol.

#define BATCH 64
#define SEQ   512
#define HID   512
#define NTHR  256
#define CB    8
#define ROWS  32
#define SLOT  (BATCH * HID)     // floats per ring slot (128KB)

typedef unsigned int u32;

__device__ __forceinline__ float dot4(const float4 a, const float4 b) {
  return a.x * b.x + a.y * b.y + a.z * b.z + a.w * b.w;
}
__device__ __forceinline__ float2 ld2(const double* p) {   // sc1 8B load
  const double d = __hip_atomic_load(p, __ATOMIC_RELAXED, __HIP_MEMORY_SCOPE_AGENT);
  return __builtin_bit_cast(float2, d);
}
__device__ __forceinline__ void st2(double* p, float2 v) { // sc1 8B store
  __hip_atomic_store(p, __builtin_bit_cast(double, v),
                     __ATOMIC_RELAXED, __HIP_MEMORY_SCOPE_AGENT);
}
__device__ __forceinline__ float tanh_fast(float x) {
  const float a = fabsf(x);
  const float e = __expf(-2.0f * a);
  const float t = (1.0f - e) * __builtin_amdgcn_rcpf(1.0f + e);
  return copysignf(t, x);
}
#define WAIT_VM0() asm volatile("s_waitcnt vmcnt(0)" ::: "memory")

#define RSTEP(D, N)                                                   \
  {                                                                   \
    const bool hi = (lane & (D)) != 0;                                \
    _Pragma("unroll")                                                 \
    for (int a = 0; a < (N); ++a) {                                   \
      const float keep = hi ? v[a + (N)] : v[a];                      \
      const float send = hi ? v[a] : v[a + (N)];                      \
      v[a] = keep + __shfl_xor(send, (D));                            \
    }                                                                 \
  }

__global__ __launch_bounds__(NTHR, 1) void rnn_persistent(
    const int* __restrict__ x, const int* __restrict__ lengths,
    const float* __restrict__ emb,
    const float* __restrict__ W_ih, const float* __restrict__ W_hh,
    const float* __restrict__ b_ih, const float* __restrict__ b_hh,
    float* __restrict__ out,
    float* h0r, float* h1r, u32* F, int ring)
{
  __shared__ __align__(16) float Xa[CB][HID];        // 16KB
  __shared__ __align__(16) float Xb[CB][HID];        // 16KB
  __shared__ __align__(16) float Xpart[CB][ROWS][4]; // 4KB
  __shared__ int Lens[CB];

  const int wg    = blockIdx.x;
  const int tid   = threadIdx.x;
  const int dom   = wg & 7;
  const int q     = wg >> 3;
  const int layer = q >> 4;
  const int rg    = q & 15;
  const int bbase = dom * CB;
  const int jbase = rg * ROWS;
  const int tj    = tid >> 6;
  const int lane  = tid & 63;

  // flags: entry (dom,layer,rg) on its own 128B line; value = #slots written
  u32* Fown = F + ((dom * 2 + layer) * 16 + rg) * 32;
  u32* F0   = F + ((dom * 2 + 0) * 16) * 32;   // + i*32
  u32* F1   = F + ((dom * 2 + 1) * 16) * 32;

  // ---- weights in registers: 8 j x (2 float4 k) x 2 mats = 128 VGPRs ----
  float4 wa[2][8], wb[2][8];
  {
    const float* WA = W_ih + layer * (HID * HID);
    const float* WB = W_hh + layer * (HID * HID);
    #pragma unroll
    for (int ji = 0; ji < 8; ++ji) {
      const int j = jbase + tj * 8 + ji;
      #pragma unroll
      for (int i = 0; i < 2; ++i) {
        const int k = i * 256 + 4 * lane;
        wa[i][ji] = *(const float4*)&WA[j * HID + k];
        wb[i][ji] = *(const float4*)&WB[j * HID + k];
      }
    }
  }
  if (tid < CB) Lens[tid] = lengths[bbase + tid];
  __syncthreads();
  int maxlen = Lens[0];
  #pragma unroll
  for (int i = 1; i < CB; ++i) maxlen = max(maxlen, Lens[i]);
  const int P     = maxlen;                       // 1..512
  const int pl0   = (P < SEQ) ? P : (SEQ - 1);    // l0's last active phase
  const int plast = layer ? P : pl0;
  int lm[4];                                      // group liveness bounds
  #pragma unroll
  for (int g = 0; g < 4; ++g) lm[g] = max(Lens[2 * g], Lens[2 * g + 1]);

  float4 bias4 = make_float4(0.f, 0.f, 0.f, 0.f);
  if (tid < 64) {
    const int jq = jbase + (tid & 7) * 4;
    bias4.x = b_ih[layer * HID + jq + 0] + b_hh[layer * HID + jq + 0];
    bias4.y = b_ih[layer * HID + jq + 1] + b_hh[layer * HID + jq + 1];
    bias4.z = b_ih[layer * HID + jq + 2] + b_hh[layer * HID + jq + 2];
    bias4.w = b_ih[layer * HID + jq + 3] + b_hh[layer * HID + jq + 3];
  }

  // ---- initial emb prefetch (t=0, l0) ----
  float4 pf[4];
  if (layer == 0) {
    #pragma unroll
    for (int i = 0; i < 4; ++i) {
      const int u = tid + NTHR * i;
      const int r = u >> 7, c = (u & 127) * 4;
      const int tok = x[(bbase + r) * SEQ];
      pf[i] = *(const float4*)&emb[(size_t)tok * HID + c];
    }
  }

  int cur = 0, prev = ring - 1;   // p % ring, (p-1) % ring

  for (int p = 0; p <= P; ++p) {
    const bool active = layer ? (p >= 1) : (p < SEQ);
    const int  wr0    = (cur + 1 == ring) ? 0 : (cur + 1);

    if (active) {
      const int t = layer ? (p - 1) : p;

      // ---- stage: sc1 ring loads -> LDS ----
      if (layer == 0) {
        const double* src = (const double*)(h0r) + (size_t)cur * (SLOT / 2);
        float2 tv[8];
        #pragma unroll
        for (int i = 0; i < 8; ++i) {
          const int u = tid + NTHR * i;
          tv[i] = ld2(&src[(size_t)(bbase + (u >> 8)) * 256 + (u & 255)]);
        }
        #pragma unroll
        for (int i = 0; i < 8; ++i) {
          const int u = tid + NTHR * i;
          *(float2*)&Xb[u >> 8][(u & 255) * 2] = tv[i];
        }
        #pragma unroll
        for (int i = 0; i < 4; ++i) {
          const int u = tid + NTHR * i;
          *(float4*)&Xa[u >> 7][(u & 127) * 4] = pf[i];
        }
      } else {
        const double* srcB = (const double*)(h1r) + (size_t)prev * (SLOT / 2);
        const double* srcA = (const double*)(h0r) + (size_t)cur  * (SLOT / 2);
        float2 tb[8], ta[8];
        #pragma unroll
        for (int i = 0; i < 8; ++i) {
          const int u = tid + NTHR * i;
          tb[i] = ld2(&srcB[(size_t)(bbase + (u >> 8)) * 256 + (u & 255)]);
        }
        #pragma unroll
        for (int i = 0; i < 8; ++i) {
          const int u = tid + NTHR * i;
          ta[i] = ld2(&srcA[(size_t)(bbase + (u >> 8)) * 256 + (u & 255)]);
        }
        #pragma unroll
        for (int i = 0; i < 8; ++i) {
          const int u = tid + NTHR * i;
          *(float2*)&Xb[u >> 8][(u & 255) * 2] = tb[i];
          *(float2*)&Xa[u >> 8][(u & 255) * 2] = ta[i];
        }
      }
      __syncthreads();

      // ---- compute: 4 groups, unroll 2; skip fully-frozen groups ----
      #pragma unroll 2
      for (int g = 0; g < 4; ++g) {
        if (t >= lm[g]) continue;            // wave-uniform (Lens shared)
        float v[16];
        #pragma unroll
        for (int o = 0; o < 16; ++o) v[o] = 0.f;
        #pragma unroll
        for (int bi = 0; bi < 2; ++bi) {
          const int b = g * 2 + bi;
          const float4 xa0 = *(const float4*)&Xa[b][4 * lane];
          const float4 xa1 = *(const float4*)&Xa[b][256 + 4 * lane];
          const float4 xb0 = *(const float4*)&Xb[b][4 * lane];
          const float4 xb1 = *(const float4*)&Xb[b][256 + 4 * lane];
          #pragma unroll
          for (int ji = 0; ji < 8; ++ji) {
            v[bi * 8 + ji] += dot4(wa[0][ji], xa0) + dot4(wa[1][ji], xa1)
                            + dot4(wb[0][ji], xb0) + dot4(wb[1][ji], xb1);
          }
        }
        RSTEP(32, 8)
        RSTEP(16, 4)
        RSTEP(8, 2)
        RSTEP(4, 1)
        const int b_o = g * 2 + (lane >> 5);
        const int j_o = tj * 8 + ((lane >> 2) & 7);
        Xpart[b_o][j_o][lane & 3] = v[0];
      }
      __syncthreads();

      // ---- finalize: sum partials, fast tanh, mask, sc1 ring store ----
      if (tid < 64) {
        const int b = tid >> 3, jq = (tid & 7) * 4;
        const float4 hb = *(const float4*)&Xb[b][jbase + jq];
        const bool live = (t < Lens[b]);
        float4 r = hb;
        if (live) {
          const float4 p0 = *(const float4*)&Xpart[b][jq + 0][0];
          const float4 p1 = *(const float4*)&Xpart[b][jq + 1][0];
          const float4 p2 = *(const float4*)&Xpart[b][jq + 2][0];
          const float4 p3 = *(const float4*)&Xpart[b][jq + 3][0];
          r.x = tanh_fast(p0.x + p0.y + p0.z + p0.w + bias4.x);
          r.y = tanh_fast(p1.x + p1.y + p1.z + p1.w + bias4.y);
          r.z = tanh_fast(p2.x + p2.y + p2.z + p2.w + bias4.z);
          r.w = tanh_fast(p3.x + p3.y + p3.z + p3.w + bias4.w);
        }
        double* dst = layer ? ((double*)h1r + (size_t)cur * (SLOT / 2))
                            : ((double*)h0r + (size_t)wr0 * (SLOT / 2));
        const size_t di = (size_t)(bbase + b) * 256 + ((jbase + jq) >> 1);
        st2(&dst[di],     make_float2(r.x, r.y));
        st2(&dst[di + 1], make_float2(r.z, r.w));
        if (p == plast) {   // fused epilogue: own tile = own output
          if (layer == 0) {
            *(float4*)&out[32768 + (size_t)(bbase + b) * 1024 + jbase + jq] = r;
          } else {
            *(float4*)&out[(size_t)(bbase + b) * 512 + jbase + jq] = r;
            *(float4*)&out[32768 + (size_t)(bbase + b) * 1024 + 512 + jbase + jq] = r;
          }
        }
      }
    }

    // ---- exchange: drain -> flag store -> prefetch -> parallel detect ----
    WAIT_VM0();
    __syncthreads();
    if (tid == 0 && active)   // l0 publishes p+1 slots, l1 publishes p
      __hip_atomic_store(Fown, (u32)(layer ? p : (p + 1)),
                         __ATOMIC_RELAXED, __HIP_MEMORY_SCOPE_AGENT);
    const int np = p + 1;
    if (layer == 0 && np <= plast) {
      #pragma unroll
      for (int i = 0; i < 4; ++i) {
        const int u = tid + NTHR * i;
        const int r = u >> 7, c = (u & 127) * 4;
        const int tok = x[(bbase + r) * SEQ + np];
        pf[i] = *(const float4*)&emb[(size_t)tok * HID + c];
      }
    }
    if (np <= P) {
      if (tid < 64) {
        u32* fp  = Fown;            // dummy for idle lanes (always valid)
        u32  tgt = 0;
        bool idle = true;
        if (lane < 16) { fp = F0 + lane * 32; tgt = (u32)np; idle = false; }
        else if (lane < 32) {
          if (layer) { fp = F1 + (lane - 16) * 32; tgt = (u32)(np - 1); idle = false; }
          else {
            const int th = np + 1 - ring;   // small-ring WAR throttle
            if (th > 0) { fp = F1 + (lane - 16) * 32; tgt = (u32)th; idle = false; }
          }
        }
        while (true) {
          const u32 vv = __hip_atomic_load(fp, __ATOMIC_RELAXED,
                                           __HIP_MEMORY_SCOPE_AGENT);
          const bool ok = idle || (vv >= tgt);
          if (__ballot(ok) == ~0ull) break;
        }
      }
      __syncthreads();
    }
    prev = cur; cur = wr0;
  }
}

extern "C" void kernel_launch(void* const* d_in, const int* in_sizes, int n_in,
                              void* d_out, int out_size, void* d_ws, size_t ws_size,
                              hipStream_t stream) {
  (void)in_sizes; (void)n_in; (void)out_size;
  const int*   x       = (const int*)d_in[0];
  const int*   lengths = (const int*)d_in[1];
  const float* emb     = (const float*)d_in[2];
  const float* W_ih    = (const float*)d_in[3];
  const float* W_hh    = (const float*)d_in[4];
  const float* b_ih    = (const float*)d_in[5];
  const float* b_hh    = (const float*)d_in[6];
  float* out = (float*)d_out;

  const size_t slotB = (size_t)SLOT * sizeof(float);            // 128KB
  const size_t needFull = 2 * (size_t)513 * slotB + 65536;      // ~131.5MB
  const int ring = (ws_size >= needFull) ? 513 : 17;            // 17: throttled

  float* h0r = (float*)d_ws;
  float* h1r = h0r + (size_t)ring * SLOT;
  u32*   F   = (u32*)(h1r + (size_t)ring * SLOT);

  // zero slot 0 of each ring (h(-1)=0) + flag page; ws re-poisoned each call
  hipMemsetAsync(h0r, 0, slotB, stream);
  hipMemsetAsync(h1r, 0, slotB, stream);
  hipMemsetAsync(F, 0, 32768, stream);

  hipLaunchKernelGGL(rnn_persistent, dim3(256), dim3(NTHR), 0, stream,
                     x, lengths, emb, W_ih, W_hh, b_ih, b_hh, out,
                     h0r, h1r, F, ring);
}